// Round 4
// baseline (233.678 us; speedup 1.0000x reference)
//
#include <hip/hip_runtime.h>
#include <stdint.h>

#define TPB 256

// d_ws layout (32-bit words from base)
#define WS_W1F   0      // 504 floats: binarized w1 as +/-1.0f, [6][3][28] (25 used per ic, 3 pad)
#define WS_W2PK  504    // 80 u32:  w2 bits, [16 oc][5 kr], bit (5c+k)
#define WS_WF1P  584    // 3000 u32: wf1 bits, [120 o][25 pos], bit oc
#define WS_WF2PK 3584   // 336 u32: wf2 bits, [84 o][4 q], bit = neuron q*32+b
#define WS_WF3PK 3920   // 30 u32:  wf3 bits, [10 o][3 q]

__global__ __launch_bounds__(TPB) void prep_kernel(
    const float* __restrict__ w1, const float* __restrict__ w2,
    const float* __restrict__ wf1, const float* __restrict__ wf2,
    const float* __restrict__ wf3, float* __restrict__ wsf,
    uint32_t* __restrict__ wsu)
{
  int id = blockIdx.x * TPB + threadIdx.x;
  if (id < 504) {
    int c = id / 84, r = id % 84, ic = r / 28, k = r % 28;
    wsf[WS_W1F + id] = (k < 25) ? ((w1[c*75 + ic*25 + k] >= 0.f) ? 1.f : -1.f) : 0.f;
  } else if (id < 584) {
    int r = id - 504, oc = r / 5, kr = r % 5;
    uint32_t w = 0;
    for (int c = 0; c < 6; ++c)
      for (int k = 0; k < 5; ++k)
        w |= (uint32_t)(w2[((oc*6 + c)*5 + kr)*5 + k] >= 0.f) << (5*c + k);
    wsu[WS_W2PK + r] = w;
  } else if (id < 3584) {
    int r = id - 584, o = r / 25, p = r % 25;
    uint32_t w = 0;
    for (int oc = 0; oc < 16; ++oc)
      w |= (uint32_t)(wf1[o*400 + oc*25 + p] >= 0.f) << oc;
    wsu[WS_WF1P + r] = w;
  } else if (id < 3920) {
    int r = id - 3584, o = r / 4, q = r % 4;
    uint32_t w = 0;
    for (int b = 0; b < 32; ++b) {
      int n = q*32 + b;
      if (n < 120) w |= (uint32_t)(wf2[o*120 + n] >= 0.f) << b;
    }
    wsu[WS_WF2PK + r] = w;
  } else if (id < 3950) {
    int r = id - 3920, o = r / 3, q = r % 3;
    uint32_t w = 0;
    for (int b = 0; b < 32; ++b) {
      int n = q*32 + b;
      if (n < 84) w |= (uint32_t)(wf3[o*84 + n] >= 0.f) << b;
    }
    wsu[WS_WF3PK + r] = w;
  }
}

// image layout: plane*1024 + row*32 + swizzled col. 16B chunks XOR'd by (row>>1)&7
// so the ~11 distinct window addresses per wave spread over all 8 bank-starts
// (<=2 distinct addrs per bank => free, per m136).
__device__ __forceinline__ int img_idx(int plane, int row, int col) {
  return (plane << 10) + (row << 5) + ((((col >> 2) ^ ((row >> 1) & 7)) << 2) | (col & 3));
}

// Fused per-3-image pipeline: conv1(fp32, zero-waste units) -> wave-parallel exact
// resolve -> conv2(popcnt) -> fc1/2/3
__global__ void __launch_bounds__(TPB)
__attribute__((amdgpu_waves_per_eu(3, 3)))
lenet_kernel(
    const float* __restrict__ x,
    const float* __restrict__ b1, const float* __restrict__ b2,
    const float* __restrict__ bf1, const float* __restrict__ bf2,
    const float* __restrict__ bf3,
    const float* __restrict__ wsf, const uint32_t* __restrict__ wsu,
    float* __restrict__ out)
{
  // image buffer overlaid with conv2 scratch (image dead after resolve pass)
  __shared__ __align__(16) union Ovl {
    float img[9216];                                         // 3 img * 3 c * 32 * 32 = 36864 B
    struct { uint32_t ppatch[3][10][10][5]; uint32_t dbuf[3][16][100]; } c2; // 25200 B
  } ovl;
  __shared__ float wsm[504];              // binarized conv1 weights [6][3][28]
  __shared__ float sb1[6];
  __shared__ float sb2[16];
  __shared__ uint32_t bits1[3][6][14];    // pooled-binarized layer1 (single writer -> plain store)
  __shared__ uint32_t border[3][6][14];   // borderline masks
  __shared__ uint32_t w2pks[16][5];
  __shared__ uint32_t bits2[3][25];
  __shared__ uint32_t wf2pks[84][4];
  __shared__ uint32_t wf3pks[10][3];
  __shared__ uint32_t bitsf1[3][4];
  __shared__ uint32_t bitsf2[3][3];
  __shared__ uint32_t rlist[256];
  __shared__ int rcnt;

  const int t = threadIdx.x;
  const long long img0 = (long long)blockIdx.x * 3;
  const int nimg = (img0 + 3 <= 8192) ? 3 : (int)(8192 - img0);

  // ---------- load phase ----------
  {
    const float4* src = (const float4*)(x + img0 * 3072);
    for (int id = t; id < nimg * 768; id += TPB) {
      int img_i = id / 768, rem = id % 768;
      int plane = img_i*3 + (rem >> 8);
      int rq = rem & 255, row = rq >> 3, q = rq & 7;
      *(float4*)&ovl.img[img_idx(plane, row, 4*q)] = src[id];
    }
    for (int id = t; id < 504; id += TPB) wsm[id] = wsf[WS_W1F + id];
    if (t < 6)  sb1[t] = b1[t];
    if (t >= 8 && t < 24) sb2[t-8] = b2[t-8];
    if (t < 80) w2pks[t/5][t%5] = wsu[WS_W2PK + t];
    if (t < 168) {
      ((uint32_t*)wf2pks)[t]       = wsu[WS_WF2PK + t];
      ((uint32_t*)wf2pks)[t + 168] = wsu[WS_WF2PK + t + 168];
    }
    if (t < 30) ((uint32_t*)wf3pks)[t] = wsu[WS_WF3PK + t];
    if (t < 252) { ((uint32_t*)bits1)[t] = 0; ((uint32_t*)border)[t] = 0; }
    if (t < 75) ((uint32_t*)bits2)[t] = 0;
    if (t < 12) ((uint32_t*)bitsf1)[t] = 0;
    if (t < 9)  ((uint32_t*)bitsf2)[t] = 0;
    if (t == 0) rcnt = 0;
  }
  __syncthreads();

  // ---------- conv1: one unit per thread = (img, c, pooled-row), all 28 cols ----------
  // 252 units / 256 threads: zero divergence, zero garbage FMAs.
  if (t < 252) {
    const int c  = t % 6;                  // adjacent-6 lanes share the window -> LDS broadcast
    const int v  = t / 6;
    const int pi = v % 14;
    const int im = v / 14;
    if (im < nimg) {
      float acc[2][28];
#pragma unroll
      for (int dr = 0; dr < 2; ++dr)
#pragma unroll
        for (int m = 0; m < 28; ++m) acc[dr][m] = 0.f;

#pragma unroll 1
      for (int ic = 0; ic < 3; ++ic) {
        float wr[28];
        const float4* wp = (const float4*)&wsm[c*84 + ic*28];
#pragma unroll
        for (int q = 0; q < 7; ++q) {
          float4 t4 = wp[q];
          wr[4*q] = t4.x; wr[4*q+1] = t4.y; wr[4*q+2] = t4.z; wr[4*q+3] = t4.w;
        }
        const int pbase = (im*3 + ic) << 10;
#pragma unroll
        for (int r = 0; r < 6; ++r) {
          const int row = 2*pi + r;
          const int s = (row >> 1) & 7;
          const int rbase = pbase + (row << 5);
          float cw[32];
#pragma unroll
          for (int q = 0; q < 8; ++q) {
            float4 t4 = *(const float4*)&ovl.img[rbase + ((q ^ s) << 2)];
            cw[4*q] = t4.x; cw[4*q+1] = t4.y; cw[4*q+2] = t4.z; cw[4*q+3] = t4.w;
          }
#pragma unroll
          for (int dr = 0; dr < 2; ++dr) {
            const int kr = r - dr;
            if (kr < 0 || kr > 4) continue;   // compile-time pruned
#pragma unroll
            for (int k = 0; k < 5; ++k) {
              const float w = wr[kr*5 + k];
#pragma unroll
              for (int m = 0; m < 28; ++m)
                acc[dr][m] = fmaf(cw[m + k], w, acc[dr][m]);
            }
          }
        }
      }

      const float bc = sb1[c];
      uint32_t nib = 0, nbord = 0;
#pragma unroll
      for (int jj = 0; jj < 14; ++jj) {
        float v4 = fmaxf(fmaxf(acc[0][2*jj], acc[0][2*jj+1]),
                         fmaxf(acc[1][2*jj], acc[1][2*jj+1]));
        float mm = v4 + bc;
        if (fabsf(mm) < 4e-3f) nbord |= 1u << jj;   // fp32 worst-case err ~3e-4
        else if (mm >= 0.f)    nib   |= 1u << jj;
      }
      bits1[im][c][pi]  = nib;    // single writer: plain stores
      border[im][c][pi] = nbord;
    }
  }
  __syncthreads();

  // ---------- borderline list build ----------
  if (t < 252) {
    uint32_t bw = ((uint32_t*)border)[t];
    while (bw) {
      int pj = __ffs(bw) - 1;
      bw &= bw - 1;
      int slot = atomicAdd(&rcnt, 1);
      if (slot < 256) rlist[slot] = (uint32_t)(t*16 + pj);
    }
  }
  __syncthreads();

  // ---------- wave-parallel exact fp64 resolve (rare: ~1 entry/block) ----------
  {
    const int cnt = min(rcnt, 256);
    const int wv = t >> 6, ln = t & 63;
    for (int e = wv; e < cnt; e += TPB/64) {
      uint32_t ent = rlist[e];
      int pj = ent & 15, word = ent >> 4;
      int pi = word % 14, cc = (word/14) % 6, im = word/84;
      int win = ln >> 4, j = ln & 15;
      int dr = win >> 1, dc = win & 1;
      double ps = 0.0;
      if (j < 15) {
        // lane covers 5 of the 75 MACs of its window
#pragma unroll
        for (int kk = 0; kk < 5; ++kk) {
          int k = j*5 + kk;
          int ic = k/25, r5 = (k%25)/5, kc = k%5;
          ps += (double)ovl.img[img_idx(im*3+ic, 2*pi + dr + r5, 2*pj + dc + kc)] *
                (double)wsm[cc*84 + ic*28 + r5*5 + kc];
        }
      }
#pragma unroll
      for (int off = 8; off >= 1; off >>= 1)
        ps += __shfl_xor(ps, off, 16);
      double m0 = __shfl(ps, 0, 64), m1 = __shfl(ps, 16, 64);
      double m2 = __shfl(ps, 32, 64), m3 = __shfl(ps, 48, 64);
      if (ln == 0) {
        double best = fmax(fmax(m0, m1), fmax(m2, m3));
        if (best + (double)sb1[cc] >= 0.0)
          atomicOr(&bits1[im][cc][pi], 1u << pj);
      }
    }
  }
  __syncthreads();

  // ---------- conv2 phase A: pack 30-bit input words per (i,j,kr) ----------
  for (int id = t; id < 1500; id += TPB) {
    const int im  = id / 500;
    const int rem = id % 500;
    const int kr = rem % 5;
    const int ij = rem / 5;
    const int i = ij / 10, j = ij % 10;
    uint32_t w = 0;
#pragma unroll
    for (int c = 0; c < 6; ++c)
      w |= ((bits1[im][c][i + kr] >> j) & 31u) << (5*c);
    ovl.c2.ppatch[im][i][j][kr] = w;
  }
  __syncthreads();

  // ---------- conv2 phase B: popcount diffs ----------
  for (int id = t; id < 4800; id += TPB) {
    const int im  = id / 1600;
    const int rem = id % 1600;
    const int oc = rem / 100;
    const int ij = rem % 100;
    int d = 0;
#pragma unroll
    for (int kr = 0; kr < 5; ++kr)
      d += __popc(ovl.c2.ppatch[im][ij/10][ij%10][kr] ^ w2pks[oc][kr]);
    ovl.c2.dbuf[im][oc][ij] = (uint32_t)d;  // s = 150 - 2d
  }
  __syncthreads();

  // ---------- conv2 phase C: maxpool + bias + binarize ----------
  for (int id = t; id < 1200; id += TPB) {
    const int im  = id / 400;
    const int rem = id % 400;
    const int oc  = rem / 25;
    const int pos = rem % 25;
    const int pi = pos / 5, pj = pos % 5;
    const uint32_t* dp = &ovl.c2.dbuf[im][oc][20*pi + 2*pj];
    uint32_t d0 = dp[0], d1 = dp[1], d2 = dp[10], d3 = dp[11];
    int dmin = (int)min(min(d0, d1), min(d2, d3));
    float v = (float)(150 - 2*dmin) + sb2[oc];
    if (v >= 0.f) atomicOr(&bits2[im][pos], 1u << oc);
  }
  __syncthreads();

  // ---------- fc1 ----------
  for (int id = t; id < 360; id += TPB) {
    const int im = id / 120;
    const int o = id % 120;
    const uint32_t* wrow = wsu + WS_WF1P + o*25;
    int d = 0;
#pragma unroll
    for (int p = 0; p < 25; ++p) d += __popc(bits2[im][p] ^ wrow[p]);
    float v = (float)(400 - 2*d) + bf1[o];
    if (v >= 0.f) atomicOr(&bitsf1[im][o >> 5], 1u << (o & 31));
  }
  __syncthreads();

  // ---------- fc2 ----------
  for (int id = t; id < 252; id += TPB) {
    const int im = id / 84;
    const int o = id % 84;
    int d = 0;
#pragma unroll
    for (int q = 0; q < 4; ++q) d += __popc(bitsf1[im][q] ^ wf2pks[o][q]);
    float v = (float)(120 - 2*d) + bf2[o];
    if (v >= 0.f) atomicOr(&bitsf2[im][o >> 5], 1u << (o & 31));
  }
  __syncthreads();

  // ---------- fc3 ----------
  for (int id = t; id < 30; id += TPB) {
    const int im = id / 10;
    const int o = id % 10;
    if (im < nimg) {
      int d = 0;
#pragma unroll
      for (int q = 0; q < 3; ++q) d += __popc(bitsf2[im][q] ^ wf3pks[o][q]);
      out[(img0 + im)*10 + o] = (float)(84 - 2*d) + bf3[o];
    }
  }
}

extern "C" void kernel_launch(void* const* d_in, const int* in_sizes, int n_in,
                              void* d_out, int out_size, void* d_ws, size_t ws_size,
                              hipStream_t stream)
{
  const float* x   = (const float*)d_in[0];
  const float* w1  = (const float*)d_in[1];
  const float* b1  = (const float*)d_in[2];
  const float* w2  = (const float*)d_in[3];
  const float* b2  = (const float*)d_in[4];
  const float* wf1 = (const float*)d_in[5];
  const float* bf1 = (const float*)d_in[6];
  const float* wf2 = (const float*)d_in[7];
  const float* bf2 = (const float*)d_in[8];
  const float* wf3 = (const float*)d_in[9];
  const float* bf3 = (const float*)d_in[10];
  float*    wsf = (float*)d_ws;
  uint32_t* wsu = (uint32_t*)d_ws;

  hipLaunchKernelGGL(prep_kernel, dim3(16), dim3(TPB), 0, stream,
                     w1, w2, wf1, wf2, wf3, wsf, wsu);
  const int nblk = (8192 + 2) / 3;
  hipLaunchKernelGGL(lenet_kernel, dim3(nblk), dim3(TPB), 0, stream,
                     x, b1, b2, bf1, bf2, bf3, wsf, wsu, (float*)d_out);
}

// Round 5
// 130.672 us; speedup vs baseline: 1.7883x; 1.7883x over previous
//
#include <hip/hip_runtime.h>
#include <stdint.h>

#define TPB 256
#define RCAP 320
#define BAND 0.05f

// d_ws layout (u32 words)
#define WS_WPK   0     // 288: packed-f16 tap pairs [6 c][3 ic][16] (kr*3+j used, j=0..2)
#define WS_W1B   288   // 18:  w1 sign bits [6 c][3 words] (bit k = ic*25+kr*5+kc)
#define WS_W2PK  306   // 80:  w2 bits [16 oc][5 kr], bit (5c+k)
#define WS_WF1P  386   // 3000: wf1 bits [120 o][25 pos], bit oc
#define WS_WF2PK 3386  // 336: wf2 bits [84 o][4 q]
#define WS_WF3PK 3722  // 30:  wf3 bits [10 o][3 q]

typedef _Float16 h2_t __attribute__((ext_vector_type(2)));

#if defined(__has_builtin)
#if __has_builtin(__builtin_amdgcn_fdot2)
#define HAVE_FDOT2 1
#endif
#endif

__device__ __forceinline__ float fd2(uint32_t a, uint32_t b, float c) {
#ifdef HAVE_FDOT2
  return __builtin_amdgcn_fdot2(__builtin_bit_cast(h2_t, a),
                                __builtin_bit_cast(h2_t, b), c, false);
#else
  h2_t ha = __builtin_bit_cast(h2_t, a), hb = __builtin_bit_cast(h2_t, b);
  return fmaf((float)ha[0], (float)hb[0], fmaf((float)ha[1], (float)hb[1], c));
#endif
}

__device__ __forceinline__ uint32_t pkf16(float a, float b) {
  uint32_t lo = (uint32_t)__builtin_bit_cast(uint16_t, (_Float16)a);
  uint32_t hi = (uint32_t)__builtin_bit_cast(uint16_t, (_Float16)b);
  return lo | (hi << 16);
}

__device__ __forceinline__ uint32_t albit(uint32_t hi, uint32_t lo) {
  return __builtin_amdgcn_alignbit(hi, lo, 16);  // (lo.hi16, hi.lo16) packed
}

// exact fp64 window sum from global x; weights as sign bits b0/b1/b2
__device__ __forceinline__ double win_sum(const float* __restrict__ xb,
                                          uint32_t b0, uint32_t b1, uint32_t b2) {
  double s = 0.0;
#pragma unroll
  for (int ic = 0; ic < 3; ++ic)
#pragma unroll
    for (int rr = 0; rr < 5; ++rr) {
      const float* rp = xb + ic * 1024 + rr * 32;
#pragma unroll
      for (int kc = 0; kc < 5; ++kc) {
        const int idx = ic * 25 + rr * 5 + kc;
        const uint32_t bw = (idx < 32) ? b0 : ((idx < 64) ? b1 : b2);
        double xv = (double)rp[kc];
        s += ((bw >> (idx & 31)) & 1u) ? xv : -xv;
      }
    }
  return s;
}

__global__ __launch_bounds__(TPB) void prep_kernel(
    const float* __restrict__ w1, const float* __restrict__ w2,
    const float* __restrict__ wf1, const float* __restrict__ wf2,
    const float* __restrict__ wf3, uint32_t* __restrict__ wsu)
{
  int id = blockIdx.x * TPB + threadIdx.x;
  if (id < 288) {
    int c = id / 48, r = id % 48, ic = r / 16, q = r % 16;
    uint32_t w = 0;
    if (q < 15) {
      int kr = q / 3, j = q % 3, k0 = 2 * j, k1 = 2 * j + 1;
      uint32_t lo = (w1[c*75 + ic*25 + kr*5 + k0] >= 0.f) ? 0x3C00u : 0xBC00u;
      uint32_t hi = (k1 < 5) ? ((w1[c*75 + ic*25 + kr*5 + k1] >= 0.f) ? 0x3C00u : 0xBC00u) : 0u;
      w = lo | (hi << 16);
    }
    wsu[WS_WPK + id] = w;
  } else if (id < 306) {
    int i = id - 288, c = i / 3, q = i % 3;
    uint32_t w = 0;
    for (int b = 0; b < 32; ++b) {
      int k = q * 32 + b;
      if (k < 75) w |= (uint32_t)(w1[c*75 + k] >= 0.f) << b;
    }
    wsu[WS_W1B + i] = w;
  } else if (id < 386) {
    int r = id - 306, oc = r / 5, kr = r % 5;
    uint32_t w = 0;
    for (int c = 0; c < 6; ++c)
      for (int k = 0; k < 5; ++k)
        w |= (uint32_t)(w2[((oc*6 + c)*5 + kr)*5 + k] >= 0.f) << (5*c + k);
    wsu[WS_W2PK + r] = w;
  } else if (id < 3386) {
    int r = id - 386, o = r / 25, p = r % 25;
    uint32_t w = 0;
    for (int oc = 0; oc < 16; ++oc)
      w |= (uint32_t)(wf1[o*400 + oc*25 + p] >= 0.f) << oc;
    wsu[WS_WF1P + r] = w;
  } else if (id < 3722) {
    int r = id - 3386, o = r / 4, q = r % 4;
    uint32_t w = 0;
    for (int b = 0; b < 32; ++b) {
      int n = q*32 + b;
      if (n < 120) w |= (uint32_t)(wf2[o*120 + n] >= 0.f) << b;
    }
    wsu[WS_WF2PK + r] = w;
  } else if (id < 3752) {
    int r = id - 3722, o = r / 3, q = r % 3;
    uint32_t w = 0;
    for (int b = 0; b < 32; ++b) {
      int n = q*32 + b;
      if (n < 84) w |= (uint32_t)(wf3[o*84 + n] >= 0.f) << b;
    }
    wsu[WS_WF3PK + r] = w;
  }
}

// Fused per-3-image pipeline: conv1(f16 dot2, f32 acc) -> exact fp64 resolve
// (from global) -> conv2(popcnt) -> fc1/2/3
__global__ void __launch_bounds__(TPB, 4) lenet_kernel(
    const float* __restrict__ x,
    const float* __restrict__ b1, const float* __restrict__ b2,
    const float* __restrict__ bf1, const float* __restrict__ bf2,
    const float* __restrict__ bf3,
    const uint32_t* __restrict__ wsu,
    float* __restrict__ out, int imgs_total)
{
  // f16 image (u32 = 2 packed cols), overlaid with conv2 scratch after conv1.
  // Row = 16 u32 (4 b128 chunks), chunk index XOR-swizzled by
  // s3 = ((row>>1)^(row>>3)^plane)&3 to spread bank starts.
  __shared__ __align__(16) union Ovl {
    uint32_t imgh[4640];                       // 9 planes * 32 rows * 16 + pad
    struct { uint32_t ppatch[3][10][10][5]; uint32_t dbuf[3][16][100]; } c2;  // 25200 B
  } ovl;
  __shared__ uint32_t wpks[288];     // [6][3][16] packed f16 tap pairs
  __shared__ uint32_t w1bs[18];      // w1 sign bits
  __shared__ float sb1[6];
  __shared__ float sb2[16];
  __shared__ uint32_t bits1[3][6][14];
  __shared__ uint32_t border_[3][6][14];
  __shared__ uint32_t w2pks[16][5];
  __shared__ uint32_t bits2[3][25];
  __shared__ uint32_t wf2pks[84][4];
  __shared__ uint32_t wf3pks[10][3];
  __shared__ uint32_t bitsf1[3][4];
  __shared__ uint32_t bitsf2[3][3];
  __shared__ uint32_t rlist[RCAP];
  __shared__ int rcnt;

  const int t = threadIdx.x;
  const long long img0 = (long long)blockIdx.x * 3;
  const int nimg = (img0 + 3 <= imgs_total) ? 3 : (int)(imgs_total - img0);

  // ---------- load + f16 pack phase (one row of 32 per thread) ----------
  {
    const int nrows = nimg * 96;               // 3 planes * 32 rows per image
    for (int rid = t; rid < 288; rid += TPB) {
      if (rid < nrows) {
        const int im = rid / 96, rr = rid % 96;
        const int p = rr >> 5, row = rr & 31;
        const float* rp = x + (img0 + im) * 3072 + p * 1024 + row * 32;
        float xs[32];
#pragma unroll
        for (int q = 0; q < 8; ++q) {
          float4 f = ((const float4*)rp)[q];
          xs[4*q] = f.x; xs[4*q+1] = f.y; xs[4*q+2] = f.z; xs[4*q+3] = f.w;
        }
        uint32_t wb[16];
#pragma unroll
        for (int j = 0; j < 16; ++j) wb[j] = pkf16(xs[2*j], xs[2*j+1]);
        const int pg = im*3 + p;
        const int s3 = ((row >> 1) ^ (row >> 3) ^ pg) & 3;
        const int rbase = ((pg << 5) + row) << 4;
#pragma unroll
        for (int q2 = 0; q2 < 4; ++q2) {
          uint4 v = make_uint4(wb[4*q2], wb[4*q2+1], wb[4*q2+2], wb[4*q2+3]);
          *(uint4*)&ovl.imgh[rbase + ((q2 ^ s3) << 2)] = v;
        }
      }
    }
    if (t < 32) ovl.imgh[4608 + t] = 0;        // zero pad (overflow reads)
    for (int id = t; id < 288; id += TPB) wpks[id] = wsu[WS_WPK + id];
    if (t < 18) w1bs[t] = wsu[WS_W1B + t];
    if (t < 6)  sb1[t] = b1[t];
    if (t >= 8 && t < 24) sb2[t-8] = b2[t-8];
    if (t < 80) w2pks[t/5][t%5] = wsu[WS_W2PK + t];
    if (t < 168) {
      ((uint32_t*)wf2pks)[t]       = wsu[WS_WF2PK + t];
      ((uint32_t*)wf2pks)[t + 168] = wsu[WS_WF2PK + t + 168];
    }
    if (t < 30) ((uint32_t*)wf3pks)[t] = wsu[WS_WF3PK + t];
    if (t < 252) { ((uint32_t*)bits1)[t] = 0; ((uint32_t*)border_)[t] = 0; }
    if (t < 75) ((uint32_t*)bits2)[t] = 0;
    if (t < 12) ((uint32_t*)bitsf1)[t] = 0;
    if (t < 9)  ((uint32_t*)bitsf2)[t] = 0;
    if (t == 0) rcnt = 0;
  }
  __syncthreads();

  // ---------- conv1: dot2 f16 x f16 -> f32 acc, unit = (im,c,pi,g) ----------
  for (int u = t; u < 1008; u += TPB) {       // 3 img * 6 c * 14 pi * 4 g
    const int c = u % 6;                      // 6 consecutive lanes share window -> broadcast
    const int s = u / 6;
    const int g = s & 3;
    const int pi = (s >> 2) % 14;
    const int im = s / 56;
    if (im >= nimg) continue;
    float acc[2][8];
#pragma unroll
    for (int dr = 0; dr < 2; ++dr)
#pragma unroll
      for (int m = 0; m < 8; ++m) acc[dr][m] = 0.f;

#pragma unroll 1
    for (int ic = 0; ic < 3; ++ic) {
      uint32_t wq[16];
      {
        const uint4* wpp = (const uint4*)&wpks[(c*3 + ic) << 4];
#pragma unroll
        for (int q = 0; q < 4; ++q) {
          uint4 W = wpp[q];
          wq[4*q] = W.x; wq[4*q+1] = W.y; wq[4*q+2] = W.z; wq[4*q+3] = W.w;
        }
      }
      const int pg = im*3 + ic;
#pragma unroll
      for (int r = 0; r < 6; ++r) {
        const int row = 2*pi + r;
        const int s3 = ((row >> 1) ^ (row >> 3) ^ pg) & 3;
        const int rb = ((pg << 5) + row) << 4;
        uint4 A = *(const uint4*)&ovl.imgh[rb + ((g ^ s3) << 2)];
        uint4 B = *(const uint4*)&ovl.imgh[rb + (((g + 1) ^ s3) << 2)];
        uint32_t P[12];
        P[0] = A.x; P[2] = A.y; P[4] = A.z; P[6] = A.w; P[8] = B.x; P[10] = B.y;
        P[1] = albit(A.y, A.x); P[3]  = albit(A.z, A.y); P[5]  = albit(A.w, A.z);
        P[7] = albit(B.x, A.w); P[9]  = albit(B.y, B.x); P[11] = albit(B.z, B.y);
#pragma unroll
        for (int dr = 0; dr < 2; ++dr) {
          const int kr = r - dr;
          if (kr < 0 || kr > 4) continue;     // compile-time pruned
          const uint32_t wA = wq[kr*3], wB = wq[kr*3 + 1], wC = wq[kr*3 + 2];
#pragma unroll
          for (int m = 0; m < 8; ++m) {
            float a0 = fd2(P[m],     wA, acc[dr][m]);
            a0       = fd2(P[m + 2], wB, a0);
            acc[dr][m] = fd2(P[m + 4], wC, a0);
          }
        }
      }
    }

    const float bc = sb1[c];
    uint32_t nib = 0, nbord = 0;
#pragma unroll
    for (int jj = 0; jj < 4; ++jj) {
      const int pj = 4*g + jj;
      if (pj < 14) {                          // g=3: jj 2,3 discarded (garbage accs)
        float v = fmaxf(fmaxf(acc[0][2*jj], acc[0][2*jj+1]),
                        fmaxf(acc[1][2*jj], acc[1][2*jj+1]));
        float mm = v + bc;
        if (fabsf(mm) < BAND)  nbord |= 1u << pj;  // f16-path worst err ~0.045
        else if (mm >= 0.f)    nib   |= 1u << pj;
      }
    }
    if (nib)   atomicOr(&bits1[im][c][pi], nib);
    if (nbord) atomicOr(&border_[im][c][pi], nbord);
  }
  __syncthreads();

  // ---------- borderline list build ----------
  if (t < 252) {
    uint32_t bw = ((uint32_t*)border_)[t];
    while (bw) {
      int pj = __ffs(bw) - 1;
      bw &= bw - 1;
      int slot = atomicAdd(&rcnt, 1);
      if (slot < RCAP) rlist[slot] = (uint32_t)(t * 16 + pj);
    }
  }
  __syncthreads();

  // ---------- exact fp64 resolve from global (one window per thread) ----------
  {
    const int cnt = min(rcnt, RCAP);
    for (int k = t; k < cnt * 4; k += TPB) {
      const int e = k >> 2, win = k & 3;
      const uint32_t ent = rlist[e];
      const int pj = ent & 15, w = ent >> 4;
      const int pi = w % 14, c = (w / 14) % 6, im = w / 84;
      const int dr = win >> 1, dc = win & 1;
      const float* xb = x + (img0 + im) * 3072 + (2*pi + dr) * 32 + (2*pj + dc);
      double s = win_sum(xb, w1bs[c*3], w1bs[c*3+1], w1bs[c*3+2]);
      double s1 = fmax(s, __shfl_xor(s, 1));
      double sm = fmax(s1, __shfl_xor(s1, 2));
      if (win == 0) {
        if (sm + (double)sb1[c] >= 0.0)
          atomicOr(&((uint32_t*)bits1)[w], 1u << pj);
      }
    }
    if (rcnt > RCAP) {  // fallback (never taken in practice): rescan all masks
      for (int id = t; id < 3528; id += TPB) {
        const int w = id / 14, pj = id % 14;
        if ((((uint32_t*)border_)[w] >> pj) & 1u) {
          const int pi = w % 14, c = (w / 14) % 6, im = w / 84;
          double best = -1e300;
          for (int dr = 0; dr < 2; ++dr)
            for (int dc = 0; dc < 2; ++dc) {
              const float* xb = x + (img0 + im) * 3072 + (2*pi + dr) * 32 + (2*pj + dc);
              double s = win_sum(xb, w1bs[c*3], w1bs[c*3+1], w1bs[c*3+2]);
              best = best > s ? best : s;
            }
          if (best + (double)sb1[c] >= 0.0)
            atomicOr(&((uint32_t*)bits1)[w], 1u << pj);
        }
      }
    }
  }
  __syncthreads();

  // ---------- conv2 phase A: pack 30-bit input words per (i,j,kr) ----------
  for (int id = t; id < 1500; id += TPB) {
    const int im  = id / 500;
    const int rem = id % 500;
    const int kr = rem % 5;
    const int ij = rem / 5;
    const int i = ij / 10, j = ij % 10;
    uint32_t w = 0;
#pragma unroll
    for (int c = 0; c < 6; ++c)
      w |= ((bits1[im][c][i + kr] >> j) & 31u) << (5*c);
    ovl.c2.ppatch[im][i][j][kr] = w;
  }
  __syncthreads();

  // ---------- conv2 phase B: popcount diffs ----------
  for (int id = t; id < 4800; id += TPB) {
    const int im  = id / 1600;
    const int rem = id % 1600;
    const int oc = rem / 100;
    const int ij = rem % 100;
    int d = 0;
#pragma unroll
    for (int kr = 0; kr < 5; ++kr)
      d += __popc(ovl.c2.ppatch[im][ij/10][ij%10][kr] ^ w2pks[oc][kr]);
    ovl.c2.dbuf[im][oc][ij] = (uint32_t)d;  // s = 150 - 2d
  }
  __syncthreads();

  // ---------- conv2 phase C: maxpool + bias + binarize ----------
  for (int id = t; id < 1200; id += TPB) {
    const int im  = id / 400;
    const int rem = id % 400;
    const int oc  = rem / 25;
    const int pos = rem % 25;
    const int pi = pos / 5, pj = pos % 5;
    const uint32_t* dp = &ovl.c2.dbuf[im][oc][20*pi + 2*pj];
    uint32_t d0 = dp[0], d1 = dp[1], d2 = dp[10], d3 = dp[11];
    int dmin = (int)min(min(d0, d1), min(d2, d3));
    float v = (float)(150 - 2*dmin) + sb2[oc];
    if (v >= 0.f) atomicOr(&bits2[im][pos], 1u << oc);
  }
  __syncthreads();

  // ---------- fc1 ----------
  for (int id = t; id < 360; id += TPB) {
    const int im = id / 120;
    const int o = id % 120;
    const uint32_t* wrow = wsu + WS_WF1P + o*25;
    int d = 0;
#pragma unroll
    for (int p = 0; p < 25; ++p) d += __popc(bits2[im][p] ^ wrow[p]);
    float v = (float)(400 - 2*d) + bf1[o];
    if (v >= 0.f) atomicOr(&bitsf1[im][o >> 5], 1u << (o & 31));
  }
  __syncthreads();

  // ---------- fc2 ----------
  for (int id = t; id < 252; id += TPB) {
    const int im = id / 84;
    const int o = id % 84;
    int d = 0;
#pragma unroll
    for (int q = 0; q < 4; ++q) d += __popc(bitsf1[im][q] ^ wf2pks[o][q]);
    float v = (float)(120 - 2*d) + bf2[o];
    if (v >= 0.f) atomicOr(&bitsf2[im][o >> 5], 1u << (o & 31));
  }
  __syncthreads();

  // ---------- fc3 ----------
  for (int id = t; id < 30; id += TPB) {
    const int im = id / 10;
    const int o = id % 10;
    if (im < nimg) {
      int d = 0;
#pragma unroll
      for (int q = 0; q < 3; ++q) d += __popc(bitsf2[im][q] ^ wf3pks[o][q]);
      out[(img0 + im)*10 + o] = (float)(84 - 2*d) + bf3[o];
    }
  }
}

extern "C" void kernel_launch(void* const* d_in, const int* in_sizes, int n_in,
                              void* d_out, int out_size, void* d_ws, size_t ws_size,
                              hipStream_t stream)
{
  const float* x   = (const float*)d_in[0];
  const float* w1  = (const float*)d_in[1];
  const float* b1  = (const float*)d_in[2];
  const float* w2  = (const float*)d_in[3];
  const float* b2  = (const float*)d_in[4];
  const float* wf1 = (const float*)d_in[5];
  const float* bf1 = (const float*)d_in[6];
  const float* wf2 = (const float*)d_in[7];
  const float* bf2 = (const float*)d_in[8];
  const float* wf3 = (const float*)d_in[9];
  const float* bf3 = (const float*)d_in[10];
  uint32_t* wsu = (uint32_t*)d_ws;

  const int imgs = in_sizes[0] / 3072;
  hipLaunchKernelGGL(prep_kernel, dim3(16), dim3(TPB), 0, stream,
                     w1, w2, wf1, wf2, wf3, wsu);
  const int nblk = (imgs + 2) / 3;
  hipLaunchKernelGGL(lenet_kernel, dim3(nblk), dim3(TPB), 0, stream,
                     x, b1, b2, bf1, bf2, bf3, wsu, (float*)d_out, imgs);
}

// Round 6
// 92.292 us; speedup vs baseline: 2.5319x; 1.4159x over previous
//
#include <hip/hip_runtime.h>
#include <stdint.h>

#define TPB 256
#define RCAP 128
#define BAND 0.05f

// d_ws layout (u32 words)
#define WS_BFR   0     // 1024: B fragments [s 4][lane 64][dw 4] (f16 pairs, +/-1 or 0)
#define WS_W1B   1024  // 18:  w1 sign bits [6 c][3 words] (bit k = ic*25+kr*5+kc)
#define WS_W2PK  1042  // 80:  w2 bits [16 oc][5 kr], bit (5c+k)
#define WS_WF1P  1122  // 3000: wf1 bits [120 o][25 pos], bit oc
#define WS_WF2PK 4122  // 336: wf2 bits [84 o][4 q]
#define WS_WF3PK 4458  // 30:  wf3 bits [10 o][3 q]  (end 4488)

typedef _Float16 half8 __attribute__((ext_vector_type(8)));
typedef float f32x4 __attribute__((ext_vector_type(4)));
typedef unsigned int u32x4 __attribute__((ext_vector_type(4)));

__device__ __forceinline__ uint32_t pkf16(float a, float b) {
  uint32_t lo = (uint32_t)__builtin_bit_cast(uint16_t, (_Float16)a);
  uint32_t hi = (uint32_t)__builtin_bit_cast(uint16_t, (_Float16)b);
  return lo | (hi << 16);
}

// exact fp64 window sum from global x; weights as sign bits b0/b1/b2
__device__ __forceinline__ double win_sum(const float* __restrict__ xb,
                                          uint32_t b0, uint32_t b1, uint32_t b2) {
  double s = 0.0;
#pragma unroll
  for (int ic = 0; ic < 3; ++ic)
#pragma unroll
    for (int rr = 0; rr < 5; ++rr) {
      const float* rp = xb + ic * 1024 + rr * 32;
#pragma unroll
      for (int kc = 0; kc < 5; ++kc) {
        const int idx = ic * 25 + rr * 5 + kc;
        const uint32_t bw = (idx < 32) ? b0 : ((idx < 64) ? b1 : b2);
        double xv = (double)rp[kc];
        s += ((bw >> (idx & 31)) & 1u) ? xv : -xv;
      }
    }
  return s;
}

__global__ __launch_bounds__(TPB) void prep_kernel(
    const float* __restrict__ w1, const float* __restrict__ w2,
    const float* __restrict__ wf1, const float* __restrict__ wf2,
    const float* __restrict__ wf3, uint32_t* __restrict__ wsu)
{
  int id = blockIdx.x * TPB + threadIdx.x;
  if (id < 1024) {
    // B fragment for MFMA step s, lane ln, dword dw (2 f16): B[k][n], n=lane&15,
    // k-octet o = 4s + (ln>>4); j = dw*2+h -> kc = (o%3)*2 + (j>>2), ic = j&3
    int s = id >> 8, r = id & 255, ln = r >> 2, dw = r & 3;
    int g4 = ln >> 4, n = ln & 15;
    int o = 4*s + g4, kr = o / 3, kcp = o % 3;
    uint32_t w = 0;
    for (int h = 0; h < 2; ++h) {
      int j = dw*2 + h;
      int kcin = j >> 2, ic = j & 3, kc = kcp*2 + kcin;
      uint32_t f = 0;
      if (o < 15 && n < 6 && ic < 3 && kc < 5)
        f = (w1[(n*3 + ic)*25 + kr*5 + kc] >= 0.f) ? 0x3C00u : 0xBC00u;
      w |= f << (16*h);
    }
    wsu[WS_BFR + id] = w;
  } else if (id < 1042) {
    int i = id - 1024, c = i / 3, q = i % 3;
    uint32_t w = 0;
    for (int b = 0; b < 32; ++b) {
      int k = q * 32 + b;
      if (k < 75) w |= (uint32_t)(w1[c*75 + k] >= 0.f) << b;
    }
    wsu[WS_W1B + i] = w;
  } else if (id < 1122) {
    int r = id - 1042, oc = r / 5, kr = r % 5;
    uint32_t w = 0;
    for (int c = 0; c < 6; ++c)
      for (int k = 0; k < 5; ++k)
        w |= (uint32_t)(w2[((oc*6 + c)*5 + kr)*5 + k] >= 0.f) << (5*c + k);
    wsu[WS_W2PK + r] = w;
  } else if (id < 4122) {
    int r = id - 1122, o = r / 25, p = r % 25;
    uint32_t w = 0;
    for (int oc = 0; oc < 16; ++oc)
      w |= (uint32_t)(wf1[o*400 + oc*25 + p] >= 0.f) << oc;
    wsu[WS_WF1P + r] = w;
  } else if (id < 4458) {
    int r = id - 4122, o = r / 4, q = r % 4;
    uint32_t w = 0;
    for (int b = 0; b < 32; ++b) {
      int n = q*32 + b;
      if (n < 120) w |= (uint32_t)(wf2[o*120 + n] >= 0.f) << b;
    }
    wsu[WS_WF2PK + r] = w;
  } else if (id < 4488) {
    int r = id - 4458, o = r / 3, q = r % 3;
    uint32_t w = 0;
    for (int b = 0; b < 32; ++b) {
      int n = q*32 + b;
      if (n < 84) w |= (uint32_t)(wf3[o*84 + n] >= 0.f) << b;
    }
    wsu[WS_WF3PK + r] = w;
  }
}

// Fused per-4-image pipeline: conv1 via f16 MFMA -> exact fp64 resolve (global)
// -> conv2(popcnt, fused pool) -> fc1/2/3
__global__ void __launch_bounds__(TPB, 4) lenet_kernel(
    const float* __restrict__ x,
    const float* __restrict__ b1, const float* __restrict__ b2,
    const float* __restrict__ bf1, const float* __restrict__ bf2,
    const float* __restrict__ bf3,
    const uint32_t* __restrict__ wsu,
    float* __restrict__ out, int imgs_total)
{
  // Image: [im 4][row 33][col 33] pixels of 8B ({f16 c0,c1} {f16 c2,0}); row 32 and
  // col 32 are zeroed pad (reachable only by zero-weight taps -> must be finite).
  // Overlaid with conv2 ppatch after conv1+resolve (image dead there).
  __shared__ __align__(16) union Ovl {
    uint32_t imgh[8712];                      // 4*33*33*2 dw = 34848 B
    uint32_t ppatch[4][10][10][5];            // 8000 B
  } ovl;
  __shared__ uint32_t w1bs[18];
  __shared__ float sb1[6];
  __shared__ float sb2[16];
  __shared__ uint32_t bits1[4][6][14];
  __shared__ uint32_t border_[4][6][14];
  __shared__ uint32_t w2pks[16][5];
  __shared__ uint32_t bits2[4][25];
  __shared__ uint32_t wf2pks[84][4];
  __shared__ uint32_t wf3pks[10][3];
  __shared__ uint32_t bitsf1[4][4];
  __shared__ uint32_t bitsf2[4][3];
  __shared__ uint32_t rlist[RCAP];
  __shared__ int rcnt;

  const int t = threadIdx.x;
  const int lane = t & 63;
  const int wv = t >> 6;                 // wave id = image slot
  const int m16 = lane & 15;
  const int g4 = lane >> 4;
  const long long img0 = (long long)blockIdx.x * 4;
  const int nimg = (img0 + 4 <= imgs_total) ? 4 : (int)(imgs_total - img0);

  // ---------- load + f16 interleave pack: thread = (im, y, xhalf) ----------
  {
    const int im = t >> 6, y = (t >> 1) & 31, xh = t & 1;
    if (im < nimg) {
      const float* rp = x + (img0 + im) * 3072 + y * 32 + xh * 16;
      float c[3][16];
#pragma unroll
      for (int p = 0; p < 3; ++p)
#pragma unroll
        for (int q = 0; q < 4; ++q) {
          float4 f = *(const float4*)(rp + p * 1024 + 4 * q);
          c[p][4*q] = f.x; c[p][4*q+1] = f.y; c[p][4*q+2] = f.z; c[p][4*q+3] = f.w;
        }
      const int rot = 2 * (im * 2 + xh);   // spread LDS write banks
#pragma unroll
      for (int i = 0; i < 16; ++i) {
        const int ie = (i + rot) & 15;
        const int pix = (im * 33 + y) * 33 + xh * 16 + ie;
        uint2 v = make_uint2(pkf16(c[0][ie], c[1][ie]), pkf16(c[2][ie], 0.f));
        *(uint2*)&ovl.imgh[2 * pix] = v;
      }
    }
    // zero pad row 32 / col 32 of every image slot
    for (int id = t; id < 260; id += TPB) {
      int pix;
      if (id < 132) { int i2 = id / 33, k = id % 33; pix = (i2 * 33 + 32) * 33 + k; }
      else { int r = id - 132; int i2 = r >> 5, yy = r & 31; pix = (i2 * 33 + yy) * 33 + 32; }
      *(uint2*)&ovl.imgh[2 * pix] = make_uint2(0u, 0u);
    }
    if (t < 18) w1bs[t] = wsu[WS_W1B + t];
    if (t < 6)  sb1[t] = b1[t];
    if (t >= 8 && t < 24) sb2[t - 8] = b2[t - 8];
    if (t < 80) w2pks[t / 5][t % 5] = wsu[WS_W2PK + t];
    if (t < 168) {
      ((uint32_t*)wf2pks)[t]       = wsu[WS_WF2PK + t];
      ((uint32_t*)wf2pks)[t + 168] = wsu[WS_WF2PK + t + 168];
    }
    if (t < 30) ((uint32_t*)wf3pks)[t] = wsu[WS_WF3PK + t];
    for (int id = t; id < 336; id += TPB) {
      ((uint32_t*)bits1)[id] = 0; ((uint32_t*)border_)[id] = 0;
    }
    if (t < 100) ((uint32_t*)bits2)[t] = 0;
    if (t < 16) ((uint32_t*)bitsf1)[t] = 0;
    if (t < 12) ((uint32_t*)bitsf2)[t] = 0;
    if (t == 0) rcnt = 0;
  }
  __syncthreads();

  // ---------- conv1: f16 MFMA, wave = image, tile = (y, xg) 16 positions ----------
  if (wv < nimg) {
    u32x4 bf[4];
#pragma unroll
    for (int s = 0; s < 4; ++s)
      bf[s] = *(const u32x4*)&wsu[WS_BFR + (s << 8) + (lane << 2)];
    const float bcr = (m16 < 6) ? b1[m16] : 0.f;
    int koffs[4];                 // pixel-offset of this lane's k-octet per step
#pragma unroll
    for (int s = 0; s < 4; ++s) {
      const int o = 4 * s + g4;   // o=15 -> kr=5,kcp=0: zero-weight pad reads
      koffs[s] = (o / 3) * 33 + (o % 3) * 2;
    }
    const int imbase = wv * 33 * 33;
    for (int pyi = 0; pyi < 14; ++pyi) {
#pragma unroll
      for (int xg = 0; xg < 2; ++xg) {
        const int pb = imbase + (2 * pyi) * 33 + xg * 12 + m16;
        f32x4 a0 = {0.f, 0.f, 0.f, 0.f}, a1 = {0.f, 0.f, 0.f, 0.f};
#pragma unroll
        for (int s = 0; s < 4; ++s) {
          const uint2* p = (const uint2*)&ovl.imgh[2 * (pb + koffs[s])];
          uint2 r0 = p[0], r1 = p[1];     // y row:   ds_read2_b64 off 0,1
          uint2 r2 = p[33], r3 = p[34];   // y+1 row: ds_read2_b64 off 33,34
          u32x4 wa = {r0.x, r0.y, r1.x, r1.y};
          u32x4 wb = {r2.x, r2.y, r3.x, r3.y};
          a0 = __builtin_amdgcn_mfma_f32_16x16x32_f16(
                 __builtin_bit_cast(half8, wa), __builtin_bit_cast(half8, bf[s]), a0, 0, 0, 0);
          a1 = __builtin_amdgcn_mfma_f32_16x16x32_f16(
                 __builtin_bit_cast(half8, wb), __builtin_bit_cast(half8, bf[s]), a1, 0, 0, 0);
        }
        if (m16 < 6) {
          // lane owns channel m16, output cols x = xg*12 + g4*4 + q
          float v0 = fmaxf(fmaxf(a0[0], a0[1]), fmaxf(a1[0], a1[1])) + bcr;
          float v1 = fmaxf(fmaxf(a0[2], a0[3]), fmaxf(a1[2], a1[3])) + bcr;
          const int px = xg * 6 + g4 * 2;
          uint32_t nib = 0, nb = 0;
          if (fabsf(v0) < BAND) nb |= 1u << px; else if (v0 >= 0.f) nib |= 1u << px;
          if (fabsf(v1) < BAND) nb |= 1u << (px + 1); else if (v1 >= 0.f) nib |= 1u << (px + 1);
          if (nib) atomicOr(&bits1[wv][m16][pyi], nib);
          if (nb)  atomicOr(&border_[wv][m16][pyi], nb);
        }
      }
    }
  }
  __syncthreads();

  // ---------- borderline list build ----------
  for (int id = t; id < 336; id += TPB) {
    uint32_t bw = ((uint32_t*)border_)[id];
    while (bw) {
      int pj = __ffs(bw) - 1;
      bw &= bw - 1;
      int slot = atomicAdd(&rcnt, 1);
      if (slot < RCAP) rlist[slot] = (uint32_t)(id * 16 + pj);
    }
  }
  __syncthreads();

  // ---------- exact fp64 resolve from global (one window per thread) ----------
  {
    const int cnt = min(rcnt, RCAP);
    for (int k = t; k < cnt * 4; k += TPB) {
      const int e = k >> 2, win = k & 3;
      const uint32_t ent = rlist[e];
      const int pj = ent & 15, w = ent >> 4;
      const int pi = w % 14, c = (w / 14) % 6, im = w / 84;
      const int dr = win >> 1, dc = win & 1;
      const float* xb = x + (img0 + im) * 3072 + (2*pi + dr) * 32 + (2*pj + dc);
      double s = win_sum(xb, w1bs[c*3], w1bs[c*3+1], w1bs[c*3+2]);
      double s1 = fmax(s, __shfl_xor(s, 1));
      double sm = fmax(s1, __shfl_xor(s1, 2));
      if (win == 0) {
        if (sm + (double)sb1[c] >= 0.0)
          atomicOr(&((uint32_t*)bits1)[w], 1u << pj);
      }
    }
    if (rcnt > RCAP) {  // fallback (never in practice): rescan all masks
      for (int id = t; id < 4704; id += TPB) {
        const int w = id / 14, pj = id % 14;
        if ((((uint32_t*)border_)[w] >> pj) & 1u) {
          const int pi = w % 14, c = (w / 14) % 6, im = w / 84;
          double best = -1e300;
          for (int dr = 0; dr < 2; ++dr)
            for (int dc = 0; dc < 2; ++dc) {
              const float* xb = x + (img0 + im) * 3072 + (2*pi + dr) * 32 + (2*pj + dc);
              double s = win_sum(xb, w1bs[c*3], w1bs[c*3+1], w1bs[c*3+2]);
              best = best > s ? best : s;
            }
          if (best + (double)sb1[c] >= 0.0)
            atomicOr(&((uint32_t*)bits1)[w], 1u << pj);
        }
      }
    }
  }
  __syncthreads();

  // ---------- conv2 phase A: pack 30-bit input words per (i,j,kr) ----------
  for (int id = t; id < 2000; id += TPB) {
    const int im  = id / 500;
    const int rem = id % 500;
    const int kr = rem % 5;
    const int ij = rem / 5;
    const int i = ij / 10, j = ij % 10;
    uint32_t w = 0;
#pragma unroll
    for (int c = 0; c < 6; ++c)
      w |= ((bits1[im][c][i + kr] >> j) & 31u) << (5*c);
    ovl.ppatch[im][i][j][kr] = w;
  }
  __syncthreads();

  // ---------- conv2 fused popcount + maxpool + bias + binarize ----------
  for (int id = t; id < 1600; id += TPB) {
    const int im  = id / 400;
    const int rem = id % 400;
    const int oc  = rem / 25;
    const int pos = rem % 25;
    const int pi = pos / 5, pj = pos % 5;
    int dmin = 1000;
#pragma unroll
    for (int dy = 0; dy < 2; ++dy)
#pragma unroll
      for (int dx = 0; dx < 2; ++dx) {
        const uint32_t* pp = ovl.ppatch[im][2*pi + dy][2*pj + dx];
        int d = 0;
#pragma unroll
        for (int kr = 0; kr < 5; ++kr) d += __popc(pp[kr] ^ w2pks[oc][kr]);
        dmin = min(dmin, d);
      }
    float v = (float)(150 - 2*dmin) + sb2[oc];
    if (v >= 0.f) atomicOr(&bits2[im][pos], 1u << oc);
  }
  __syncthreads();

  // ---------- fc1 ----------
  for (int id = t; id < 480; id += TPB) {
    const int im = id / 120;
    const int o = id % 120;
    const uint32_t* wrow = wsu + WS_WF1P + o*25;
    int d = 0;
#pragma unroll
    for (int p = 0; p < 25; ++p) d += __popc(bits2[im][p] ^ wrow[p]);
    float v = (float)(400 - 2*d) + bf1[o];
    if (v >= 0.f) atomicOr(&bitsf1[im][o >> 5], 1u << (o & 31));
  }
  __syncthreads();

  // ---------- fc2 ----------
  for (int id = t; id < 336; id += TPB) {
    const int im = id / 84;
    const int o = id % 84;
    int d = 0;
#pragma unroll
    for (int q = 0; q < 4; ++q) d += __popc(bitsf1[im][q] ^ wf2pks[o][q]);
    float v = (float)(120 - 2*d) + bf2[o];
    if (v >= 0.f) atomicOr(&bitsf2[im][o >> 5], 1u << (o & 31));
  }
  __syncthreads();

  // ---------- fc3 ----------
  for (int id = t; id < 40; id += TPB) {
    const int im = id / 10;
    const int o = id % 10;
    if (im < nimg) {
      int d = 0;
#pragma unroll
      for (int q = 0; q < 3; ++q) d += __popc(bitsf2[im][q] ^ wf3pks[o][q]);
      out[(img0 + im)*10 + o] = (float)(84 - 2*d) + bf3[o];
    }
  }
}

extern "C" void kernel_launch(void* const* d_in, const int* in_sizes, int n_in,
                              void* d_out, int out_size, void* d_ws, size_t ws_size,
                              hipStream_t stream)
{
  const float* x   = (const float*)d_in[0];
  const float* w1  = (const float*)d_in[1];
  const float* b1  = (const float*)d_in[2];
  const float* w2  = (const float*)d_in[3];
  const float* b2  = (const float*)d_in[4];
  const float* wf1 = (const float*)d_in[5];
  const float* bf1 = (const float*)d_in[6];
  const float* wf2 = (const float*)d_in[7];
  const float* bf2 = (const float*)d_in[8];
  const float* wf3 = (const float*)d_in[9];
  const float* bf3 = (const float*)d_in[10];
  uint32_t* wsu = (uint32_t*)d_ws;

  const int imgs = in_sizes[0] / 3072;
  hipLaunchKernelGGL(prep_kernel, dim3(18), dim3(TPB), 0, stream,
                     w1, w2, wf1, wf2, wf3, wsu);
  const int nblk = (imgs + 3) / 4;
  hipLaunchKernelGGL(lenet_kernel, dim3(nblk), dim3(TPB), 0, stream,
                     x, b1, b2, bf1, bf2, bf3, wsu, (float*)d_out, imgs);
}

// Round 7
// 73.885 us; speedup vs baseline: 3.1627x; 1.2491x over previous
//
#include <hip/hip_runtime.h>
#include <stdint.h>

#define TPB 256
#define RCAP 128
#define BAND 0.05f

// d_ws layout (u32 words)
#define WS_BFR   0     // 1024: B fragments [s 4][lane 64][dw 4] (f16 pairs, +/-1 or 0)
#define WS_W1B   1024  // 18:  w1 sign bits [6 c][3 words] (bit k = ic*25+kr*5+kc)
#define WS_W2PK  1042  // 80:  w2 bits [16 oc][5 kr], bit (5c+k)
#define WS_WF1P  1122  // 3000: wf1 bits [120 o][25 pos], bit oc
#define WS_WF2PK 4122  // 336: wf2 bits [84 o][4 q]
#define WS_WF3PK 4458  // 30:  wf3 bits [10 o][3 q]  (end 4488)

typedef _Float16 half8 __attribute__((ext_vector_type(8)));
typedef float f32x4 __attribute__((ext_vector_type(4)));
typedef unsigned int u32x4 __attribute__((ext_vector_type(4)));

__device__ __forceinline__ uint32_t pkf16(float a, float b) {
  uint32_t lo = (uint32_t)__builtin_bit_cast(uint16_t, (_Float16)a);
  uint32_t hi = (uint32_t)__builtin_bit_cast(uint16_t, (_Float16)b);
  return lo | (hi << 16);
}

// exact fp64 window sum from global x; weights as sign bits b0/b1/b2
__device__ __forceinline__ double win_sum(const float* __restrict__ xb,
                                          uint32_t b0, uint32_t b1, uint32_t b2) {
  double s = 0.0;
#pragma unroll
  for (int ic = 0; ic < 3; ++ic)
#pragma unroll
    for (int rr = 0; rr < 5; ++rr) {
      const float* rp = xb + ic * 1024 + rr * 32;
#pragma unroll
      for (int kc = 0; kc < 5; ++kc) {
        const int idx = ic * 25 + rr * 5 + kc;
        const uint32_t bw = (idx < 32) ? b0 : ((idx < 64) ? b1 : b2);
        double xv = (double)rp[kc];
        s += ((bw >> (idx & 31)) & 1u) ? xv : -xv;
      }
    }
  return s;
}

__global__ __launch_bounds__(TPB) void prep_kernel(
    const float* __restrict__ w1, const float* __restrict__ w2,
    const float* __restrict__ wf1, const float* __restrict__ wf2,
    const float* __restrict__ wf3, uint32_t* __restrict__ wsu)
{
  int id = blockIdx.x * TPB + threadIdx.x;
  if (id < 1024) {
    // B fragment for MFMA step s, lane ln, dword dw (2 f16): B[k][n], n=lane&15,
    // k-octet o = 4s + (ln>>4); j = dw*2+h -> kc = (o%3)*2 + (j>>2), ic = j&3
    int s = id >> 8, r = id & 255, ln = r >> 2, dw = r & 3;
    int g4 = ln >> 4, n = ln & 15;
    int o = 4*s + g4, kr = o / 3, kcp = o % 3;
    uint32_t w = 0;
    for (int h = 0; h < 2; ++h) {
      int j = dw*2 + h;
      int kcin = j >> 2, ic = j & 3, kc = kcp*2 + kcin;
      uint32_t f = 0;
      if (o < 15 && n < 6 && ic < 3 && kc < 5)
        f = (w1[(n*3 + ic)*25 + kr*5 + kc] >= 0.f) ? 0x3C00u : 0xBC00u;
      w |= f << (16*h);
    }
    wsu[WS_BFR + id] = w;
  } else if (id < 1042) {
    int i = id - 1024, c = i / 3, q = i % 3;
    uint32_t w = 0;
    for (int b = 0; b < 32; ++b) {
      int k = q * 32 + b;
      if (k < 75) w |= (uint32_t)(w1[c*75 + k] >= 0.f) << b;
    }
    wsu[WS_W1B + i] = w;
  } else if (id < 1122) {
    int r = id - 1042, oc = r / 5, kr = r % 5;
    uint32_t w = 0;
    for (int c = 0; c < 6; ++c)
      for (int k = 0; k < 5; ++k)
        w |= (uint32_t)(w2[((oc*6 + c)*5 + kr)*5 + k] >= 0.f) << (5*c + k);
    wsu[WS_W2PK + r] = w;
  } else if (id < 4122) {
    int r = id - 1122, o = r / 25, p = r % 25;
    uint32_t w = 0;
    for (int oc = 0; oc < 16; ++oc)
      w |= (uint32_t)(wf1[o*400 + oc*25 + p] >= 0.f) << oc;
    wsu[WS_WF1P + r] = w;
  } else if (id < 4458) {
    int r = id - 4122, o = r / 4, q = r % 4;
    uint32_t w = 0;
    for (int b = 0; b < 32; ++b) {
      int n = q*32 + b;
      if (n < 120) w |= (uint32_t)(wf2[o*120 + n] >= 0.f) << b;
    }
    wsu[WS_WF2PK + r] = w;
  } else if (id < 4488) {
    int r = id - 4458, o = r / 3, q = r % 3;
    uint32_t w = 0;
    for (int b = 0; b < 32; ++b) {
      int n = q*32 + b;
      if (n < 84) w |= (uint32_t)(wf3[o*84 + n] >= 0.f) << b;
    }
    wsu[WS_WF3PK + r] = w;
  }
}

// Fused per-4-image pipeline: conv1 via f16 MFMA -> exact fp64 resolve (global)
// -> conv2(popcnt, fused pool) -> fc1/2/3
__global__ void __launch_bounds__(TPB, 4) lenet_kernel(
    const float* __restrict__ x,
    const float* __restrict__ b1, const float* __restrict__ b2,
    const float* __restrict__ bf1, const float* __restrict__ bf2,
    const float* __restrict__ bf3,
    const uint32_t* __restrict__ wsu,
    float* __restrict__ out, int imgs_total)
{
  // Image: [im 4][row 33][col 33] pixels of 8B ({f16 c0,c1} {f16 c2,0}); row 32 and
  // col 32 are zeroed pad (reachable only by zero-weight taps -> must be finite).
  // Overlaid with conv2 ppatch after conv1+resolve (image dead there).
  __shared__ __align__(16) union Ovl {
    uint32_t imgh[8712];                      // 4*33*33*2 dw = 34848 B
    uint32_t ppatch[4][10][10][5];            // 8000 B
  } ovl;
  __shared__ uint32_t w1bs[18];
  __shared__ float sb1[6];
  __shared__ float sb2[16];
  __shared__ uint32_t bits1[4][6][14];
  __shared__ uint32_t border_[4][6][14];
  __shared__ uint32_t w2pks[16][5];
  __shared__ uint32_t bits2[4][25];
  __shared__ uint32_t wf2pks[84][4];
  __shared__ uint32_t wf3pks[10][3];
  __shared__ uint32_t bitsf1[4][4];
  __shared__ uint32_t bitsf2[4][3];
  __shared__ uint32_t rlist[RCAP];
  __shared__ int rcnt;

  const int t = threadIdx.x;
  const int lane = t & 63;
  const int wv = t >> 6;                 // wave id = image slot
  const int m16 = lane & 15;
  const int g4 = lane >> 4;
  const long long img0 = (long long)blockIdx.x * 4;
  const int nimg = (img0 + 4 <= imgs_total) ? 4 : (int)(imgs_total - img0);

  // ---------- load + f16 interleave pack: thread = (im, y, xhalf) ----------
  // Fully static indexing (NO per-thread arrays -> no scratch; rule #20).
  {
    const int im = t >> 6, y = (t >> 1) & 31, xh = t & 1;
    if (im < nimg) {
      const float* rp = x + (img0 + im) * 3072 + y * 32 + xh * 16;
      const int pixbase = (im * 33 + y) * 33 + xh * 16;
#pragma unroll
      for (int q = 0; q < 4; ++q) {
        float4 f0 = *(const float4*)(rp +    0 + 4 * q);
        float4 f1 = *(const float4*)(rp + 1024 + 4 * q);
        float4 f2 = *(const float4*)(rp + 2048 + 4 * q);
        uint32_t* d = &ovl.imgh[2 * (pixbase + 4 * q)];
        *(uint2*)(d + 0) = make_uint2(pkf16(f0.x, f1.x), pkf16(f2.x, 0.f));
        *(uint2*)(d + 2) = make_uint2(pkf16(f0.y, f1.y), pkf16(f2.y, 0.f));
        *(uint2*)(d + 4) = make_uint2(pkf16(f0.z, f1.z), pkf16(f2.z, 0.f));
        *(uint2*)(d + 6) = make_uint2(pkf16(f0.w, f1.w), pkf16(f2.w, 0.f));
      }
    }
    // zero pad row 32 / col 32 of every image slot
    for (int id = t; id < 260; id += TPB) {
      int pix;
      if (id < 132) { int i2 = id / 33, k = id % 33; pix = (i2 * 33 + 32) * 33 + k; }
      else { int r = id - 132; int i2 = r >> 5, yy = r & 31; pix = (i2 * 33 + yy) * 33 + 32; }
      *(uint2*)&ovl.imgh[2 * pix] = make_uint2(0u, 0u);
    }
    if (t < 18) w1bs[t] = wsu[WS_W1B + t];
    if (t < 6)  sb1[t] = b1[t];
    if (t >= 8 && t < 24) sb2[t - 8] = b2[t - 8];
    if (t < 80) w2pks[t / 5][t % 5] = wsu[WS_W2PK + t];
    if (t < 168) {
      ((uint32_t*)wf2pks)[t]       = wsu[WS_WF2PK + t];
      ((uint32_t*)wf2pks)[t + 168] = wsu[WS_WF2PK + t + 168];
    }
    if (t < 30) ((uint32_t*)wf3pks)[t] = wsu[WS_WF3PK + t];
    for (int id = t; id < 336; id += TPB) {
      ((uint32_t*)bits1)[id] = 0; ((uint32_t*)border_)[id] = 0;
    }
    if (t < 100) ((uint32_t*)bits2)[t] = 0;
    if (t < 16) ((uint32_t*)bitsf1)[t] = 0;
    if (t < 12) ((uint32_t*)bitsf2)[t] = 0;
    if (t == 0) rcnt = 0;
  }
  __syncthreads();

  // ---------- conv1: f16 MFMA, wave = image, tile = (y, xg) 16 positions ----------
  if (wv < nimg) {
    u32x4 bf[4];
#pragma unroll
    for (int s = 0; s < 4; ++s)
      bf[s] = *(const u32x4*)&wsu[WS_BFR + (s << 8) + (lane << 2)];
    const float bcr = sb1[(m16 < 6) ? m16 : 0];
    int koffs[4];                 // pixel-offset of this lane's k-octet per step
#pragma unroll
    for (int s = 0; s < 4; ++s) {
      const int o = 4 * s + g4;   // o=15 -> kr=5,kcp=0: zero-weight pad reads
      koffs[s] = (o / 3) * 33 + (o % 3) * 2;
    }
    const int imbase = wv * 33 * 33;
    for (int pyi = 0; pyi < 14; ++pyi) {
#pragma unroll
      for (int xg = 0; xg < 2; ++xg) {
        const int pb = imbase + (2 * pyi) * 33 + xg * 12 + m16;
        f32x4 a0 = {0.f, 0.f, 0.f, 0.f}, a1 = {0.f, 0.f, 0.f, 0.f};
#pragma unroll
        for (int s = 0; s < 4; ++s) {
          const uint2* p = (const uint2*)&ovl.imgh[2 * (pb + koffs[s])];
          uint2 r0 = p[0], r1 = p[1];     // y row:   ds_read2_b64 off 0,1
          uint2 r2 = p[33], r3 = p[34];   // y+1 row: ds_read2_b64 off 33,34
          u32x4 wa = {r0.x, r0.y, r1.x, r1.y};
          u32x4 wb = {r2.x, r2.y, r3.x, r3.y};
          a0 = __builtin_amdgcn_mfma_f32_16x16x32_f16(
                 __builtin_bit_cast(half8, wa), __builtin_bit_cast(half8, bf[s]), a0, 0, 0, 0);
          a1 = __builtin_amdgcn_mfma_f32_16x16x32_f16(
                 __builtin_bit_cast(half8, wb), __builtin_bit_cast(half8, bf[s]), a1, 0, 0, 0);
        }
        if (m16 < 6) {
          // lane owns channel m16, output cols x = xg*12 + g4*4 + q
          float v0 = fmaxf(fmaxf(a0[0], a0[1]), fmaxf(a1[0], a1[1])) + bcr;
          float v1 = fmaxf(fmaxf(a0[2], a0[3]), fmaxf(a1[2], a1[3])) + bcr;
          const int px = xg * 6 + g4 * 2;
          uint32_t nib = 0, nb = 0;
          if (fabsf(v0) < BAND) nb |= 1u << px; else if (v0 >= 0.f) nib |= 1u << px;
          if (fabsf(v1) < BAND) nb |= 1u << (px + 1); else if (v1 >= 0.f) nib |= 1u << (px + 1);
          if (nib) atomicOr(&bits1[wv][m16][pyi], nib);
          if (nb)  atomicOr(&border_[wv][m16][pyi], nb);
        }
      }
    }
  }
  __syncthreads();

  // ---------- borderline list build ----------
  for (int id = t; id < 336; id += TPB) {
    uint32_t bw = ((uint32_t*)border_)[id];
    while (bw) {
      int pj = __ffs(bw) - 1;
      bw &= bw - 1;
      int slot = atomicAdd(&rcnt, 1);
      if (slot < RCAP) rlist[slot] = (uint32_t)(id * 16 + pj);
    }
  }
  __syncthreads();

  // ---------- exact fp64 resolve from global (one window per thread) ----------
  {
    const int cnt = min(rcnt, RCAP);
    for (int k = t; k < cnt * 4; k += TPB) {
      const int e = k >> 2, win = k & 3;
      const uint32_t ent = rlist[e];
      const int pj = ent & 15, w = ent >> 4;
      const int pi = w % 14, c = (w / 14) % 6, im = w / 84;
      const int dr = win >> 1, dc = win & 1;
      const float* xb = x + (img0 + im) * 3072 + (2*pi + dr) * 32 + (2*pj + dc);
      double s = win_sum(xb, w1bs[c*3], w1bs[c*3+1], w1bs[c*3+2]);
      double s1 = fmax(s, __shfl_xor(s, 1));
      double sm = fmax(s1, __shfl_xor(s1, 2));
      if (win == 0) {
        if (sm + (double)sb1[c] >= 0.0)
          atomicOr(&((uint32_t*)bits1)[w], 1u << pj);
      }
    }
    if (rcnt > RCAP) {  // fallback (never in practice): rescan all masks
      for (int id = t; id < 4704; id += TPB) {
        const int w = id / 14, pj = id % 14;
        if ((((uint32_t*)border_)[w] >> pj) & 1u) {
          const int pi = w % 14, c = (w / 14) % 6, im = w / 84;
          double best = -1e300;
          for (int dr = 0; dr < 2; ++dr)
            for (int dc = 0; dc < 2; ++dc) {
              const float* xb = x + (img0 + im) * 3072 + (2*pi + dr) * 32 + (2*pj + dc);
              double s = win_sum(xb, w1bs[c*3], w1bs[c*3+1], w1bs[c*3+2]);
              best = best > s ? best : s;
            }
          if (best + (double)sb1[c] >= 0.0)
            atomicOr(&((uint32_t*)bits1)[w], 1u << pj);
        }
      }
    }
  }
  __syncthreads();

  // ---------- conv2 phase A: pack 30-bit input words per (i,j,kr) ----------
  for (int id = t; id < 2000; id += TPB) {
    const int im  = id / 500;
    const int rem = id % 500;
    const int kr = rem % 5;
    const int ij = rem / 5;
    const int i = ij / 10, j = ij % 10;
    uint32_t w = 0;
#pragma unroll
    for (int c = 0; c < 6; ++c)
      w |= ((bits1[im][c][i + kr] >> j) & 31u) << (5*c);
    ovl.ppatch[im][i][j][kr] = w;
  }
  __syncthreads();

  // ---------- conv2 fused popcount + maxpool + bias + binarize ----------
  for (int id = t; id < 1600; id += TPB) {
    const int im  = id / 400;
    const int rem = id % 400;
    const int oc  = rem / 25;
    const int pos = rem % 25;
    const int pi = pos / 5, pj = pos % 5;
    int dmin = 1000;
#pragma unroll
    for (int dy = 0; dy < 2; ++dy)
#pragma unroll
      for (int dx = 0; dx < 2; ++dx) {
        const uint32_t* pp = ovl.ppatch[im][2*pi + dy][2*pj + dx];
        int d = 0;
#pragma unroll
        for (int kr = 0; kr < 5; ++kr) d += __popc(pp[kr] ^ w2pks[oc][kr]);
        dmin = min(dmin, d);
      }
    float v = (float)(150 - 2*dmin) + sb2[oc];
    if (v >= 0.f) atomicOr(&bits2[im][pos], 1u << oc);
  }
  __syncthreads();

  // ---------- fc1 ----------
  for (int id = t; id < 480; id += TPB) {
    const int im = id / 120;
    const int o = id % 120;
    const uint32_t* wrow = wsu + WS_WF1P + o*25;
    int d = 0;
#pragma unroll
    for (int p = 0; p < 25; ++p) d += __popc(bits2[im][p] ^ wrow[p]);
    float v = (float)(400 - 2*d) + bf1[o];
    if (v >= 0.f) atomicOr(&bitsf1[im][o >> 5], 1u << (o & 31));
  }
  __syncthreads();

  // ---------- fc2 ----------
  for (int id = t; id < 336; id += TPB) {
    const int im = id / 84;
    const int o = id % 84;
    int d = 0;
#pragma unroll
    for (int q = 0; q < 4; ++q) d += __popc(bitsf1[im][q] ^ wf2pks[o][q]);
    float v = (float)(120 - 2*d) + bf2[o];
    if (v >= 0.f) atomicOr(&bitsf2[im][o >> 5], 1u << (o & 31));
  }
  __syncthreads();

  // ---------- fc3 ----------
  for (int id = t; id < 40; id += TPB) {
    const int im = id / 10;
    const int o = id % 10;
    if (im < nimg) {
      int d = 0;
#pragma unroll
      for (int q = 0; q < 3; ++q) d += __popc(bitsf2[im][q] ^ wf3pks[q == 0 ? o : o][q]);
      out[(img0 + im)*10 + o] = (float)(84 - 2*d) + bf3[o];
    }
  }
}

extern "C" void kernel_launch(void* const* d_in, const int* in_sizes, int n_in,
                              void* d_out, int out_size, void* d_ws, size_t ws_size,
                              hipStream_t stream)
{
  const float* x   = (const float*)d_in[0];
  const float* w1  = (const float*)d_in[1];
  const float* b1  = (const float*)d_in[2];
  const float* w2  = (const float*)d_in[3];
  const float* b2  = (const float*)d_in[4];
  const float* wf1 = (const float*)d_in[5];
  const float* bf1 = (const float*)d_in[6];
  const float* wf2 = (const float*)d_in[7];
  const float* bf2 = (const float*)d_in[8];
  const float* wf3 = (const float*)d_in[9];
  const float* bf3 = (const float*)d_in[10];
  uint32_t* wsu = (uint32_t*)d_ws;

  const int imgs = in_sizes[0] / 3072;
  hipLaunchKernelGGL(prep_kernel, dim3(18), dim3(TPB), 0, stream,
                     w1, w2, wf1, wf2, wf3, wsu);
  const int nblk = (imgs + 3) / 4;
  hipLaunchKernelGGL(lenet_kernel, dim3(nblk), dim3(TPB), 0, stream,
                     x, b1, b2, bf1, bf2, bf3, wsu, (float*)d_out, imgs);
}

// Round 8
// 69.912 us; speedup vs baseline: 3.3425x; 1.0568x over previous
//
#include <hip/hip_runtime.h>
#include <stdint.h>

#define TPB 256
#define RCAP 128
#define BAND 0.05f

// d_ws layout (u32 words)
#define WS_BFR   0     // 1280: B fragments [s 5][lane 64][dw 4] (f16, n=2c+dy trick)
#define WS_W1B   1280  // 18:  w1 sign bits [6 c][3 words] (bit k = ic*25+kr*5+kc)
#define WS_W2PK  1298  // 80:  w2 bits [16 oc][5 kr], bit (5c+k)
#define WS_WF1P  1378  // 3000: wf1 bits [120 o][25 pos], bit oc
#define WS_WF2PK 4378  // 336: wf2 bits [84 o][4 q]
#define WS_WF3PK 4714  // 30:  wf3 bits [10 o][3 q]  (end 4744)

typedef _Float16 half8 __attribute__((ext_vector_type(8)));
typedef float f32x4 __attribute__((ext_vector_type(4)));
typedef unsigned int u32x4 __attribute__((ext_vector_type(4)));

__device__ __forceinline__ uint32_t pkf16(float a, float b) {
  uint32_t lo = (uint32_t)__builtin_bit_cast(uint16_t, (_Float16)a);
  uint32_t hi = (uint32_t)__builtin_bit_cast(uint16_t, (_Float16)b);
  return lo | (hi << 16);
}

// exact fp64 window sum from global x; weights as sign bits b0/b1/b2
__device__ __forceinline__ double win_sum(const float* __restrict__ xb,
                                          uint32_t b0, uint32_t b1, uint32_t b2) {
  double s = 0.0;
#pragma unroll
  for (int ic = 0; ic < 3; ++ic)
#pragma unroll
    for (int rr = 0; rr < 5; ++rr) {
      const float* rp = xb + ic * 1024 + rr * 32;
#pragma unroll
      for (int kc = 0; kc < 5; ++kc) {
        const int idx = ic * 25 + rr * 5 + kc;
        const uint32_t bw = (idx < 32) ? b0 : ((idx < 64) ? b1 : b2);
        double xv = (double)rp[kc];
        s += ((bw >> (idx & 31)) & 1u) ? xv : -xv;
      }
    }
  return s;
}

__global__ __launch_bounds__(TPB) void prep_kernel(
    const float* __restrict__ w1, const float* __restrict__ w2,
    const float* __restrict__ wf1, const float* __restrict__ wf2,
    const float* __restrict__ wf3, uint32_t* __restrict__ wsu)
{
  int id = blockIdx.x * TPB + threadIdx.x;
  if (id < 1280) {
    // B fragment, dy-in-N: n = 2c+dy (n<12). k-octet o = 4s+g4 -> input row
    // r6 = o/3 (0..5), col-pair cp = o%3. k-slot j2 = dw*2+h ->
    // ic = j2&3, pixel = j2>>2, kc = cp*2+pixel; tap kr = r6-dy must be 0..4.
    int s = id >> 8, r = id & 255, ln = r >> 2, dw = r & 3;
    int g4 = ln >> 4, n = ln & 15;
    int o = 4 * s + g4, r6 = o / 3, cp = o % 3;
    int c = n >> 1, dy = n & 1;
    uint32_t w = 0;
    for (int h = 0; h < 2; ++h) {
      int j2 = dw * 2 + h;
      int ic = j2 & 3, pix = j2 >> 2, kc = cp * 2 + pix, kr = r6 - dy;
      uint32_t f = 0;
      if (n < 12 && o < 18 && ic < 3 && kc < 5 && kr >= 0 && kr <= 4)
        f = (w1[(c * 3 + ic) * 25 + kr * 5 + kc] >= 0.f) ? 0x3C00u : 0xBC00u;
      w |= f << (16 * h);
    }
    wsu[WS_BFR + id] = w;
  } else if (id < 1298) {
    int i = id - 1280, c = i / 3, q = i % 3;
    uint32_t w = 0;
    for (int b = 0; b < 32; ++b) {
      int k = q * 32 + b;
      if (k < 75) w |= (uint32_t)(w1[c*75 + k] >= 0.f) << b;
    }
    wsu[WS_W1B + i] = w;
  } else if (id < 1378) {
    int r = id - 1298, oc = r / 5, kr = r % 5;
    uint32_t w = 0;
    for (int c = 0; c < 6; ++c)
      for (int k = 0; k < 5; ++k)
        w |= (uint32_t)(w2[((oc*6 + c)*5 + kr)*5 + k] >= 0.f) << (5*c + k);
    wsu[WS_W2PK + r] = w;
  } else if (id < 4378) {
    int r = id - 1378, o = r / 25, p = r % 25;
    uint32_t w = 0;
    for (int oc = 0; oc < 16; ++oc)
      w |= (uint32_t)(wf1[o*400 + oc*25 + p] >= 0.f) << oc;
    wsu[WS_WF1P + r] = w;
  } else if (id < 4714) {
    int r = id - 4378, o = r / 4, q = r % 4;
    uint32_t w = 0;
    for (int b = 0; b < 32; ++b) {
      int n = q*32 + b;
      if (n < 120) w |= (uint32_t)(wf2[o*120 + n] >= 0.f) << b;
    }
    wsu[WS_WF2PK + r] = w;
  } else if (id < 4744) {
    int r = id - 4714, o = r / 3, q = r % 3;
    uint32_t w = 0;
    for (int b = 0; b < 32; ++b) {
      int n = q*32 + b;
      if (n < 84) w |= (uint32_t)(wf3[o*84 + n] >= 0.f) << b;
    }
    wsu[WS_WF3PK + r] = w;
  }
}

// Fused per-4-image pipeline: conv1 via f16 MFMA (dy-in-N) -> exact fp64 resolve
// -> conv2(popcnt, fused pool) -> fc1/2/3
__global__ void __launch_bounds__(TPB, 4) lenet_kernel(
    const float* __restrict__ x,
    const float* __restrict__ b1, const float* __restrict__ b2,
    const float* __restrict__ bf1, const float* __restrict__ bf2,
    const float* __restrict__ bf3,
    const uint32_t* __restrict__ wsu,
    float* __restrict__ out, int imgs_total)
{
  // Image: [im 4][row 32][col 33] pixels of 8B ({f16 c0,c1} {f16 c2,0});
  // col 32 zeroed pad (read only by zero-weight kc=5 taps -> must be finite).
  // Overlaid with conv2 ppatch after conv1+resolve.
  __shared__ __align__(16) union Ovl {
    uint32_t imgh[8448];                      // 4*32*33*2 dw = 33792 B
    uint32_t ppatch[4][10][10][5];            // 8000 B
  } ovl;
  __shared__ uint32_t w1bs[18];
  __shared__ float sb1[6];
  __shared__ float sb2[16];
  __shared__ uint32_t bits1[4][6][14];
  __shared__ uint32_t border_[4][6][14];
  __shared__ uint32_t w2pks[16][5];
  __shared__ uint32_t bits2[4][25];
  __shared__ uint32_t wf2pks[84][4];
  __shared__ uint32_t wf3pks[10][3];
  __shared__ uint32_t bitsf1[4][4];
  __shared__ uint32_t bitsf2[4][3];
  __shared__ uint32_t rlist[RCAP];
  __shared__ int rcnt;

  const int t = threadIdx.x;
  const int lane = t & 63;
  const int wv = t >> 6;                 // wave id = image slot
  const int m16 = lane & 15;             // A-row = x position
  const int g4 = lane >> 4;              // k-octet group
  const long long img0 = (long long)blockIdx.x * 4;
  const int nimg = (img0 + 4 <= imgs_total) ? 4 : (int)(imgs_total - img0);

  // ---------- load + f16 interleave pack (fully static indexing) ----------
  {
    const int im = t >> 6, y = (t >> 1) & 31, xh = t & 1;
    if (im < nimg) {
      const float* rp = x + (img0 + im) * 3072 + y * 32 + xh * 16;
      const int pixbase = (im * 32 + y) * 33 + xh * 16;
#pragma unroll
      for (int q = 0; q < 4; ++q) {
        float4 f0 = *(const float4*)(rp +    0 + 4 * q);
        float4 f1 = *(const float4*)(rp + 1024 + 4 * q);
        float4 f2 = *(const float4*)(rp + 2048 + 4 * q);
        uint32_t* d = &ovl.imgh[2 * (pixbase + 4 * q)];
        *(uint2*)(d + 0) = make_uint2(pkf16(f0.x, f1.x), pkf16(f2.x, 0.f));
        *(uint2*)(d + 2) = make_uint2(pkf16(f0.y, f1.y), pkf16(f2.y, 0.f));
        *(uint2*)(d + 4) = make_uint2(pkf16(f0.z, f1.z), pkf16(f2.z, 0.f));
        *(uint2*)(d + 6) = make_uint2(pkf16(f0.w, f1.w), pkf16(f2.w, 0.f));
      }
    }
    // zero pad col 32 of every row
    for (int id = t; id < 128; id += TPB) {
      int i2 = id >> 5, yy = id & 31;
      *(uint2*)&ovl.imgh[2 * ((i2 * 32 + yy) * 33 + 32)] = make_uint2(0u, 0u);
    }
    if (t < 18) w1bs[t] = wsu[WS_W1B + t];
    if (t < 6)  sb1[t] = b1[t];
    if (t >= 8 && t < 24) sb2[t - 8] = b2[t - 8];
    if (t < 80) w2pks[t / 5][t % 5] = wsu[WS_W2PK + t];
    if (t < 168) {
      ((uint32_t*)wf2pks)[t]       = wsu[WS_WF2PK + t];
      ((uint32_t*)wf2pks)[t + 168] = wsu[WS_WF2PK + t + 168];
    }
    if (t < 30) ((uint32_t*)wf3pks)[t] = wsu[WS_WF3PK + t];
    for (int id = t; id < 336; id += TPB) {
      ((uint32_t*)bits1)[id] = 0; ((uint32_t*)border_)[id] = 0;
    }
    if (t < 100) ((uint32_t*)bits2)[t] = 0;
    if (t < 16) ((uint32_t*)bitsf1)[t] = 0;
    if (t < 12) ((uint32_t*)bitsf2)[t] = 0;
    if (t == 0) rcnt = 0;
  }
  __syncthreads();

  // ---------- conv1: f16 MFMA dy-in-N; wave = image; per pyi: 2 xg chains ----------
  if (wv < nimg) {
    u32x4 bf[5];
#pragma unroll
    for (int s = 0; s < 5; ++s)
      bf[s] = *(const u32x4*)&wsu[WS_BFR + (s << 8) + (lane << 2)];
    int koffs[5];                 // pixel offset of this lane's k-octet per step
#pragma unroll
    for (int s = 0; s < 5; ++s) {
      const int o = 4 * s + g4;
      koffs[s] = (o < 18) ? (o / 3) * 33 + (o % 3) * 2 : 0;  // o>=18: B=0, any finite pixel
    }
    const int n = m16;
    const int c = n >> 1;
    const float bcr = sb1[(n < 12) ? c : 0];
    for (int pyi = 0; pyi < 14; ++pyi) {
      const int rowpix = (wv * 32 + 2 * pyi) * 33 + m16;
      f32x4 aX = {0.f, 0.f, 0.f, 0.f}, aY = {0.f, 0.f, 0.f, 0.f};
#pragma unroll
      for (int s = 0; s < 5; ++s) {
        const uint2* pX = (const uint2*)&ovl.imgh[2 * (rowpix + koffs[s])];
        const uint2* pY = (const uint2*)&ovl.imgh[2 * (rowpix + 12 + koffs[s])];
        uint2 x0 = pX[0], x1 = pX[1];
        uint2 y0 = pY[0], y1 = pY[1];
        u32x4 wa = {x0.x, x0.y, x1.x, x1.y};
        u32x4 wb = {y0.x, y0.y, y1.x, y1.y};
        aX = __builtin_amdgcn_mfma_f32_16x16x32_f16(
               __builtin_bit_cast(half8, wa), __builtin_bit_cast(half8, bf[s]), aX, 0, 0, 0);
        aY = __builtin_amdgcn_mfma_f32_16x16x32_f16(
               __builtin_bit_cast(half8, wb), __builtin_bit_cast(half8, bf[s]), aY, 0, 0, 0);
      }
      // x-pair pool in-lane (rows g4*4+q), dy-pair pool via shfl_xor(1)
      float pX0 = fmaxf(aX[0], aX[1]), pX1 = fmaxf(aX[2], aX[3]);
      float pY0 = fmaxf(aY[0], aY[1]), pY1 = fmaxf(aY[2], aY[3]);
      float qX0 = fmaxf(pX0, __shfl_xor(pX0, 1));
      float qX1 = fmaxf(pX1, __shfl_xor(pX1, 1));
      float qY0 = fmaxf(pY0, __shfl_xor(pY0, 1));
      float qY1 = fmaxf(pY1, __shfl_xor(pY1, 1));
      // lane with dy==0 (n even, n<12) owns channel c, pooled cols:
      //   xg0: px = g4*2+{0,1};  xg1: px = 6+g4*2+{0,1}
      uint32_t comb = 0;
      {
        float v0 = qX0 + bcr, v1 = qX1 + bcr, v2 = qY0 + bcr, v3 = qY1 + bcr;
        const int p0 = g4 * 2, p1 = g4 * 2 + 1, p2 = 6 + g4 * 2, p3 = 7 + g4 * 2;
        if (fabsf(v0) < BAND) comb |= 1u << (16 + p0); else if (v0 >= 0.f) comb |= 1u << p0;
        if (fabsf(v1) < BAND) comb |= 1u << (16 + p1); else if (v1 >= 0.f) comb |= 1u << p1;
        if (fabsf(v2) < BAND) comb |= 1u << (16 + p2); else if (v2 >= 0.f) comb |= 1u << p2;
        if (fabsf(v3) < BAND) comb |= 1u << (16 + p3); else if (v3 >= 0.f) comb |= 1u << p3;
      }
      // OR-reduce across the 4 g4 groups, then single plain store (no atomics)
      comb |= __shfl_xor(comb, 16);
      comb |= __shfl_xor(comb, 32);
      if (g4 == 0 && n < 12 && (n & 1) == 0) {
        bits1[wv][c][pyi]   = comb & 0x3FFFu;
        border_[wv][c][pyi] = comb >> 16;
      }
    }
  }
  __syncthreads();

  // ---------- borderline list build ----------
  for (int id = t; id < 336; id += TPB) {
    uint32_t bw = ((uint32_t*)border_)[id];
    while (bw) {
      int pj = __ffs(bw) - 1;
      bw &= bw - 1;
      int slot = atomicAdd(&rcnt, 1);
      if (slot < RCAP) rlist[slot] = (uint32_t)(id * 16 + pj);
    }
  }
  __syncthreads();

  // ---------- exact fp64 resolve from global (one window per thread) ----------
  {
    const int cnt = min(rcnt, RCAP);
    for (int k = t; k < cnt * 4; k += TPB) {
      const int e = k >> 2, win = k & 3;
      const uint32_t ent = rlist[e];
      const int pj = ent & 15, w = ent >> 4;
      const int pi = w % 14, c = (w / 14) % 6, im = w / 84;
      const int dr = win >> 1, dc = win & 1;
      const float* xb = x + (img0 + im) * 3072 + (2*pi + dr) * 32 + (2*pj + dc);
      double s = win_sum(xb, w1bs[c*3], w1bs[c*3+1], w1bs[c*3+2]);
      double s1 = fmax(s, __shfl_xor(s, 1));
      double sm = fmax(s1, __shfl_xor(s1, 2));
      if (win == 0) {
        if (sm + (double)sb1[c] >= 0.0)
          atomicOr(&((uint32_t*)bits1)[w], 1u << pj);
      }
    }
    if (rcnt > RCAP) {  // fallback (never in practice): rescan all masks
      for (int id = t; id < 4704; id += TPB) {
        const int w = id / 14, pj = id % 14;
        if ((((uint32_t*)border_)[w] >> pj) & 1u) {
          const int pi = w % 14, c = (w / 14) % 6, im = w / 84;
          double best = -1e300;
          for (int dr = 0; dr < 2; ++dr)
            for (int dc = 0; dc < 2; ++dc) {
              const float* xb = x + (img0 + im) * 3072 + (2*pi + dr) * 32 + (2*pj + dc);
              double s = win_sum(xb, w1bs[c*3], w1bs[c*3+1], w1bs[c*3+2]);
              best = best > s ? best : s;
            }
          if (best + (double)sb1[c] >= 0.0)
            atomicOr(&((uint32_t*)bits1)[w], 1u << pj);
        }
      }
    }
  }
  __syncthreads();

  // ---------- conv2 phase A: pack 30-bit input words per (i,j,kr) ----------
  for (int id = t; id < 2000; id += TPB) {
    const int im  = id / 500;
    const int rem = id % 500;
    const int kr = rem % 5;
    const int ij = rem / 5;
    const int i = ij / 10, j = ij % 10;
    uint32_t w = 0;
#pragma unroll
    for (int c = 0; c < 6; ++c)
      w |= ((bits1[im][c][i + kr] >> j) & 31u) << (5*c);
    ovl.ppatch[im][i][j][kr] = w;
  }
  __syncthreads();

  // ---------- conv2 fused popcount + maxpool + bias + binarize ----------
  for (int id = t; id < 1600; id += TPB) {
    const int im  = id / 400;
    const int rem = id % 400;
    const int oc  = rem / 25;
    const int pos = rem % 25;
    const int pi = pos / 5, pj = pos % 5;
    int dmin = 1000;
#pragma unroll
    for (int dy = 0; dy < 2; ++dy)
#pragma unroll
      for (int dx = 0; dx < 2; ++dx) {
        const uint32_t* pp = ovl.ppatch[im][2*pi + dy][2*pj + dx];
        int d = 0;
#pragma unroll
        for (int kr = 0; kr < 5; ++kr) d += __popc(pp[kr] ^ w2pks[oc][kr]);
        dmin = min(dmin, d);
      }
    float v = (float)(150 - 2*dmin) + sb2[oc];
    if (v >= 0.f) atomicOr(&bits2[im][pos], 1u << oc);
  }
  __syncthreads();

  // ---------- fc1 ----------
  for (int id = t; id < 480; id += TPB) {
    const int im = id / 120;
    const int o = id % 120;
    const uint32_t* wrow = wsu + WS_WF1P + o*25;
    int d = 0;
#pragma unroll
    for (int p = 0; p < 25; ++p) d += __popc(bits2[im][p] ^ wrow[p]);
    float v = (float)(400 - 2*d) + bf1[o];
    if (v >= 0.f) atomicOr(&bitsf1[im][o >> 5], 1u << (o & 31));
  }
  __syncthreads();

  // ---------- fc2 ----------
  for (int id = t; id < 336; id += TPB) {
    const int im = id / 84;
    const int o = id % 84;
    int d = 0;
#pragma unroll
    for (int q = 0; q < 4; ++q) d += __popc(bitsf1[im][q] ^ wf2pks[o][q]);
    float v = (float)(120 - 2*d) + bf2[o];
    if (v >= 0.f) atomicOr(&bitsf2[im][o >> 5], 1u << (o & 31));
  }
  __syncthreads();

  // ---------- fc3 ----------
  for (int id = t; id < 40; id += TPB) {
    const int im = id / 10;
    const int o = id % 10;
    if (im < nimg) {
      int d = 0;
#pragma unroll
      for (int q = 0; q < 3; ++q) d += __popc(bitsf2[im][q] ^ wf3pks[o][q]);
      out[(img0 + im)*10 + o] = (float)(84 - 2*d) + bf3[o];
    }
  }
}

extern "C" void kernel_launch(void* const* d_in, const int* in_sizes, int n_in,
                              void* d_out, int out_size, void* d_ws, size_t ws_size,
                              hipStream_t stream)
{
  const float* x   = (const float*)d_in[0];
  const float* w1  = (const float*)d_in[1];
  const float* b1  = (const float*)d_in[2];
  const float* w2  = (const float*)d_in[3];
  const float* b2  = (const float*)d_in[4];
  const float* wf1 = (const float*)d_in[5];
  const float* bf1 = (const float*)d_in[6];
  const float* wf2 = (const float*)d_in[7];
  const float* bf2 = (const float*)d_in[8];
  const float* wf3 = (const float*)d_in[9];
  const float* bf3 = (const float*)d_in[10];
  uint32_t* wsu = (uint32_t*)d_ws;

  const int imgs = in_sizes[0] / 3072;
  hipLaunchKernelGGL(prep_kernel, dim3(19), dim3(TPB), 0, stream,
                     w1, w2, wf1, wf2, wf3, wsu);
  const int nblk = (imgs + 3) / 4;
  hipLaunchKernelGGL(lenet_kernel, dim3(nblk), dim3(TPB), 0, stream,
                     x, b1, b2, bf1, bf2, bf3, wsu, (float*)d_out, imgs);
}

// Round 9
// 67.159 us; speedup vs baseline: 3.4795x; 1.0410x over previous
//
#include <hip/hip_runtime.h>
#include <stdint.h>

#define TPB 64
#define RCAP 64
#define BAND 0.05f

// d_ws layout (u32 words) — unchanged from round 8
#define WS_BFR   0     // 1280: B fragments [s 5][lane 64][dw 4] (f16, n=2c+dy trick)
#define WS_W1B   1280  // 18:  w1 sign bits [6 c][3 words] (bit k = ic*25+kr*5+kc)
#define WS_W2PK  1298  // 80:  w2 bits [16 oc][5 kr], bit (5c+k)
#define WS_WF1P  1378  // 3000: wf1 bits [120 o][25 pos], bit oc
#define WS_WF2PK 4378  // 336: wf2 bits [84 o][4 q]
#define WS_WF3PK 4714  // 30:  wf3 bits [10 o][3 q]  (end 4744)

typedef _Float16 half8 __attribute__((ext_vector_type(8)));
typedef float f32x4 __attribute__((ext_vector_type(4)));
typedef unsigned int u32x4 __attribute__((ext_vector_type(4)));

__device__ __forceinline__ uint32_t pkf16(float a, float b) {
  uint32_t lo = (uint32_t)__builtin_bit_cast(uint16_t, (_Float16)a);
  uint32_t hi = (uint32_t)__builtin_bit_cast(uint16_t, (_Float16)b);
  return lo | (hi << 16);
}

// exact fp64 window sum from global x; weights as sign bits b0/b1/b2
__device__ __forceinline__ double win_sum(const float* __restrict__ xb,
                                          uint32_t b0, uint32_t b1, uint32_t b2) {
  double s = 0.0;
#pragma unroll
  for (int ic = 0; ic < 3; ++ic)
#pragma unroll
    for (int rr = 0; rr < 5; ++rr) {
      const float* rp = xb + ic * 1024 + rr * 32;
#pragma unroll
      for (int kc = 0; kc < 5; ++kc) {
        const int idx = ic * 25 + rr * 5 + kc;
        const uint32_t bw = (idx < 32) ? b0 : ((idx < 64) ? b1 : b2);
        double xv = (double)rp[kc];
        s += ((bw >> (idx & 31)) & 1u) ? xv : -xv;
      }
    }
  return s;
}

__global__ __launch_bounds__(256) void prep_kernel(
    const float* __restrict__ w1, const float* __restrict__ w2,
    const float* __restrict__ wf1, const float* __restrict__ wf2,
    const float* __restrict__ wf3, uint32_t* __restrict__ wsu)
{
  int id = blockIdx.x * 256 + threadIdx.x;
  if (id < 1280) {
    // B fragment, dy-in-N: n = 2c+dy (n<12). k-octet o = 4s+g4 -> input row
    // r6 = o/3 (0..5), col-pair cp = o%3. k-slot j2 = dw*2+h ->
    // ic = j2&3, pixel = j2>>2, kc = cp*2+pixel; tap kr = r6-dy must be 0..4.
    int s = id >> 8, r = id & 255, ln = r >> 2, dw = r & 3;
    int g4 = ln >> 4, n = ln & 15;
    int o = 4 * s + g4, r6 = o / 3, cp = o % 3;
    int c = n >> 1, dy = n & 1;
    uint32_t w = 0;
    for (int h = 0; h < 2; ++h) {
      int j2 = dw * 2 + h;
      int ic = j2 & 3, pix = j2 >> 2, kc = cp * 2 + pix, kr = r6 - dy;
      uint32_t f = 0;
      if (n < 12 && o < 18 && ic < 3 && kc < 5 && kr >= 0 && kr <= 4)
        f = (w1[(c * 3 + ic) * 25 + kr * 5 + kc] >= 0.f) ? 0x3C00u : 0xBC00u;
      w |= f << (16 * h);
    }
    wsu[WS_BFR + id] = w;
  } else if (id < 1298) {
    int i = id - 1280, c = i / 3, q = i % 3;
    uint32_t w = 0;
    for (int b = 0; b < 32; ++b) {
      int k = q * 32 + b;
      if (k < 75) w |= (uint32_t)(w1[c*75 + k] >= 0.f) << b;
    }
    wsu[WS_W1B + i] = w;
  } else if (id < 1378) {
    int r = id - 1298, oc = r / 5, kr = r % 5;
    uint32_t w = 0;
    for (int c = 0; c < 6; ++c)
      for (int k = 0; k < 5; ++k)
        w |= (uint32_t)(w2[((oc*6 + c)*5 + kr)*5 + k] >= 0.f) << (5*c + k);
    wsu[WS_W2PK + r] = w;
  } else if (id < 4378) {
    int r = id - 1378, o = r / 25, p = r % 25;
    uint32_t w = 0;
    for (int oc = 0; oc < 16; ++oc)
      w |= (uint32_t)(wf1[o*400 + oc*25 + p] >= 0.f) << oc;
    wsu[WS_WF1P + r] = w;
  } else if (id < 4714) {
    int r = id - 4378, o = r / 4, q = r % 4;
    uint32_t w = 0;
    for (int b = 0; b < 32; ++b) {
      int n = q*32 + b;
      if (n < 120) w |= (uint32_t)(wf2[o*120 + n] >= 0.f) << b;
    }
    wsu[WS_WF2PK + r] = w;
  } else if (id < 4744) {
    int r = id - 4714, o = r / 3, q = r % 3;
    uint32_t w = 0;
    for (int b = 0; b < 32; ++b) {
      int n = q*32 + b;
      if (n < 84) w |= (uint32_t)(wf3[o*84 + n] >= 0.f) << b;
    }
    wsu[WS_WF3PK + r] = w;
  }
}

// One wave = one block = one image, end-to-end. All __syncthreads are
// intra-wave (single-wave WG) -> no cross-wave barrier coupling; 16 free-
// running waves/CU hide each other's HBM/LDS/MFMA latencies.
__global__ void __launch_bounds__(TPB, 4) lenet_kernel(
    const float* __restrict__ x,
    const float* __restrict__ b1, const float* __restrict__ b2,
    const float* __restrict__ bf1, const float* __restrict__ bf2,
    const float* __restrict__ bf3,
    const uint32_t* __restrict__ wsu,
    float* __restrict__ out)
{
  // Image: [row 32][col 33] pixels of 8B ({f16 c0,c1} {f16 c2,0}); col 32
  // zeroed pad. Overlaid with conv2 ppatch after conv1+resolve.
  __shared__ __align__(16) union Ovl {
    uint32_t imgh[2112];                      // 32*33*2 dw = 8448 B
    uint32_t ppatch[10][10][5];               // 2000 B
  } ovl;
  __shared__ uint32_t w2pks[16][5];
  __shared__ uint32_t w1bs[18];
  __shared__ float sb1[6];
  __shared__ float sb2[16];
  __shared__ uint32_t bits1[6][14];
  __shared__ uint32_t border_[6][14];
  __shared__ uint32_t bits2[25];
  __shared__ uint32_t bitsf1[4];
  __shared__ uint32_t bitsf2[3];
  __shared__ uint32_t rlist[RCAP];
  __shared__ int rcnt;

  const int t = threadIdx.x;                  // lane 0..63
  const int m16 = t & 15;                     // A-row = x position
  const int g4 = t >> 4;                      // k-octet group
  const long long img = blockIdx.x;

  // conv1 B fragments + per-step k-octet offsets (global, L3-resident)
  u32x4 bf[5];
#pragma unroll
  for (int s = 0; s < 5; ++s)
    bf[s] = *(const u32x4*)&wsu[WS_BFR + (s << 8) + (t << 2)];
  int koffs[5];
#pragma unroll
  for (int s = 0; s < 5; ++s) {
    const int o = 4 * s + g4;
    koffs[s] = (o < 18) ? (o / 3) * 33 + (o % 3) * 2 : 0;  // o>=18: B=0
  }

  // ---------- load + f16 interleave pack (fully static indexing) ----------
  {
    const int y = t >> 1, xh = t & 1;
    const float* rp = x + img * 3072 + y * 32 + xh * 16;
    const int pixbase = y * 33 + xh * 16;
#pragma unroll
    for (int q = 0; q < 4; ++q) {
      float4 f0 = *(const float4*)(rp +    0 + 4 * q);
      float4 f1 = *(const float4*)(rp + 1024 + 4 * q);
      float4 f2 = *(const float4*)(rp + 2048 + 4 * q);
      uint32_t* d = &ovl.imgh[2 * (pixbase + 4 * q)];
      *(uint2*)(d + 0) = make_uint2(pkf16(f0.x, f1.x), pkf16(f2.x, 0.f));
      *(uint2*)(d + 2) = make_uint2(pkf16(f0.y, f1.y), pkf16(f2.y, 0.f));
      *(uint2*)(d + 4) = make_uint2(pkf16(f0.z, f1.z), pkf16(f2.z, 0.f));
      *(uint2*)(d + 6) = make_uint2(pkf16(f0.w, f1.w), pkf16(f2.w, 0.f));
    }
    if (t < 32)  // zero pad col 32 of every row
      *(uint2*)&ovl.imgh[2 * (t * 33 + 32)] = make_uint2(0u, 0u);
    for (int id = t; id < 80; id += TPB) w2pks[id / 5][id % 5] = wsu[WS_W2PK + id];
    if (t < 18) w1bs[t] = wsu[WS_W1B + t];
    if (t < 6)  sb1[t] = b1[t];
    if (t >= 32 && t < 48) sb2[t - 32] = b2[t - 32];
    for (int id = t; id < 84; id += TPB) {
      ((uint32_t*)bits1)[id] = 0; ((uint32_t*)border_)[id] = 0;
    }
    if (t < 25) bits2[t] = 0;
    if (t >= 25 && t < 29) bitsf1[t - 25] = 0;
    if (t >= 29 && t < 32) bitsf2[t - 29] = 0;
    if (t == 63) rcnt = 0;
  }
  __syncthreads();

  // ---------- conv1: f16 MFMA dy-in-N; per pyi: 2 interleaved xg chains ----------
  {
    const int n = m16;
    const int c = n >> 1;
    const float bcr = sb1[(n < 12) ? c : 0];
    for (int pyi = 0; pyi < 14; ++pyi) {
      const int rowpix = (2 * pyi) * 33 + m16;
      f32x4 aX = {0.f, 0.f, 0.f, 0.f}, aY = {0.f, 0.f, 0.f, 0.f};
#pragma unroll
      for (int s = 0; s < 5; ++s) {
        const uint2* pX = (const uint2*)&ovl.imgh[2 * (rowpix + koffs[s])];
        const uint2* pY = (const uint2*)&ovl.imgh[2 * (rowpix + 12 + koffs[s])];
        uint2 x0 = pX[0], x1 = pX[1];
        uint2 y0 = pY[0], y1 = pY[1];
        u32x4 wa = {x0.x, x0.y, x1.x, x1.y};
        u32x4 wb = {y0.x, y0.y, y1.x, y1.y};
        aX = __builtin_amdgcn_mfma_f32_16x16x32_f16(
               __builtin_bit_cast(half8, wa), __builtin_bit_cast(half8, bf[s]), aX, 0, 0, 0);
        aY = __builtin_amdgcn_mfma_f32_16x16x32_f16(
               __builtin_bit_cast(half8, wb), __builtin_bit_cast(half8, bf[s]), aY, 0, 0, 0);
      }
      // x-pair pool in-lane (rows g4*4+q), dy-pair pool via shfl_xor(1)
      float pX0 = fmaxf(aX[0], aX[1]), pX1 = fmaxf(aX[2], aX[3]);
      float pY0 = fmaxf(aY[0], aY[1]), pY1 = fmaxf(aY[2], aY[3]);
      float qX0 = fmaxf(pX0, __shfl_xor(pX0, 1));
      float qX1 = fmaxf(pX1, __shfl_xor(pX1, 1));
      float qY0 = fmaxf(pY0, __shfl_xor(pY0, 1));
      float qY1 = fmaxf(pY1, __shfl_xor(pY1, 1));
      uint32_t comb = 0;
      {
        float v0 = qX0 + bcr, v1 = qX1 + bcr, v2 = qY0 + bcr, v3 = qY1 + bcr;
        const int p0 = g4 * 2, p1 = g4 * 2 + 1, p2 = 6 + g4 * 2, p3 = 7 + g4 * 2;
        if (fabsf(v0) < BAND) comb |= 1u << (16 + p0); else if (v0 >= 0.f) comb |= 1u << p0;
        if (fabsf(v1) < BAND) comb |= 1u << (16 + p1); else if (v1 >= 0.f) comb |= 1u << p1;
        if (fabsf(v2) < BAND) comb |= 1u << (16 + p2); else if (v2 >= 0.f) comb |= 1u << p2;
        if (fabsf(v3) < BAND) comb |= 1u << (16 + p3); else if (v3 >= 0.f) comb |= 1u << p3;
      }
      comb |= __shfl_xor(comb, 16);
      comb |= __shfl_xor(comb, 32);
      if (g4 == 0 && n < 12 && (n & 1) == 0) {
        bits1[c][pyi]   = comb & 0x3FFFu;
        border_[c][pyi] = comb >> 16;
      }
    }
  }
  __syncthreads();

  // ---------- borderline list build ----------
  for (int id = t; id < 84; id += TPB) {
    uint32_t bw = ((uint32_t*)border_)[id];
    while (bw) {
      int pj = __ffs(bw) - 1;
      bw &= bw - 1;
      int slot = atomicAdd(&rcnt, 1);
      if (slot < RCAP) rlist[slot] = (uint32_t)(id * 16 + pj);
    }
  }
  __syncthreads();

  // ---------- exact fp64 resolve from global (one window per lane) ----------
  {
    const int cnt = min(rcnt, RCAP);
    for (int k = t; k < cnt * 4; k += TPB) {
      const int e = k >> 2, win = k & 3;
      const uint32_t ent = rlist[e];
      const int pj = ent & 15, w = ent >> 4;
      const int pi = w % 14, c = w / 14;
      const int dr = win >> 1, dc = win & 1;
      const float* xb = x + img * 3072 + (2*pi + dr) * 32 + (2*pj + dc);
      double s = win_sum(xb, w1bs[c*3], w1bs[c*3+1], w1bs[c*3+2]);
      double s1 = fmax(s, __shfl_xor(s, 1));
      double sm = fmax(s1, __shfl_xor(s1, 2));
      if (win == 0) {
        if (sm + (double)sb1[c] >= 0.0)
          atomicOr(&((uint32_t*)bits1)[w], 1u << pj);
      }
    }
    if (rcnt > RCAP) {  // fallback (never in practice): rescan all masks
      for (int id = t; id < 1176; id += TPB) {
        const int w = id / 14, pj = id % 14;
        if ((((uint32_t*)border_)[w] >> pj) & 1u) {
          const int pi = w % 14, c = w / 14;
          double best = -1e300;
          for (int dr = 0; dr < 2; ++dr)
            for (int dc = 0; dc < 2; ++dc) {
              const float* xb = x + img * 3072 + (2*pi + dr) * 32 + (2*pj + dc);
              double s = win_sum(xb, w1bs[c*3], w1bs[c*3+1], w1bs[c*3+2]);
              best = best > s ? best : s;
            }
          if (best + (double)sb1[c] >= 0.0)
            atomicOr(&((uint32_t*)bits1)[w], 1u << pj);
        }
      }
    }
  }
  __syncthreads();

  // ---------- conv2 phase A: pack 30-bit input words per (i,j,kr) ----------
  for (int id = t; id < 500; id += TPB) {
    const int kr = id % 5;
    const int ij = id / 5;
    const int i = ij / 10, j = ij % 10;
    uint32_t w = 0;
#pragma unroll
    for (int c = 0; c < 6; ++c)
      w |= ((bits1[c][i + kr] >> j) & 31u) << (5*c);
    ovl.ppatch[i][j][kr] = w;
  }
  __syncthreads();

  // ---------- conv2 fused popcount + maxpool + bias + binarize ----------
  for (int id = t; id < 400; id += TPB) {
    const int oc  = id / 25;
    const int pos = id % 25;
    const int pi = pos / 5, pj = pos % 5;
    int dmin = 1000;
#pragma unroll
    for (int dy = 0; dy < 2; ++dy)
#pragma unroll
      for (int dx = 0; dx < 2; ++dx) {
        const uint32_t* pp = ovl.ppatch[2*pi + dy][2*pj + dx];
        int d = 0;
#pragma unroll
        for (int kr = 0; kr < 5; ++kr) d += __popc(pp[kr] ^ w2pks[oc][kr]);
        dmin = min(dmin, d);
      }
    float v = (float)(150 - 2*dmin) + sb2[oc];
    if (v >= 0.f) atomicOr(&bits2[pos], 1u << oc);
  }
  __syncthreads();

  // ---------- fc1 (wf1 rows read direct from global; L3-resident) ----------
  for (int id = t; id < 120; id += TPB) {
    const int o = id;
    const uint32_t* wrow = wsu + WS_WF1P + o*25;
    int d = 0;
#pragma unroll
    for (int p = 0; p < 25; ++p) d += __popc(bits2[p] ^ wrow[p]);
    float v = (float)(400 - 2*d) + bf1[o];
    if (v >= 0.f) atomicOr(&bitsf1[o >> 5], 1u << (o & 31));
  }
  __syncthreads();

  // ---------- fc2 ----------
  for (int id = t; id < 84; id += TPB) {
    const int o = id;
    int d = 0;
#pragma unroll
    for (int q = 0; q < 4; ++q)
      d += __popc(bitsf1[q] ^ wsu[WS_WF2PK + o*4 + q]);
    float v = (float)(120 - 2*d) + bf2[o];
    if (v >= 0.f) atomicOr(&bitsf2[o >> 5], 1u << (o & 31));
  }
  __syncthreads();

  // ---------- fc3 ----------
  if (t < 10) {
    const int o = t;
    int d = 0;
#pragma unroll
    for (int q = 0; q < 3; ++q)
      d += __popc(bitsf2[q] ^ wsu[WS_WF3PK + o*3 + q]);
    out[img*10 + o] = (float)(84 - 2*d) + bf3[o];
  }
}

extern "C" void kernel_launch(void* const* d_in, const int* in_sizes, int n_in,
                              void* d_out, int out_size, void* d_ws, size_t ws_size,
                              hipStream_t stream)
{
  const float* x   = (const float*)d_in[0];
  const float* w1  = (const float*)d_in[1];
  const float* b1  = (const float*)d_in[2];
  const float* w2  = (const float*)d_in[3];
  const float* b2  = (const float*)d_in[4];
  const float* wf1 = (const float*)d_in[5];
  const float* bf1 = (const float*)d_in[6];
  const float* wf2 = (const float*)d_in[7];
  const float* bf2 = (const float*)d_in[8];
  const float* wf3 = (const float*)d_in[9];
  const float* bf3 = (const float*)d_in[10];
  uint32_t* wsu = (uint32_t*)d_ws;

  const int imgs = in_sizes[0] / 3072;
  hipLaunchKernelGGL(prep_kernel, dim3(19), dim3(256), 0, stream,
                     w1, w2, wf1, wf2, wf3, wsu);
  hipLaunchKernelGGL(lenet_kernel, dim3(imgs), dim3(TPB), 0, stream,
                     x, b1, b2, bf1, bf2, bf3, wsu, (float*)d_out);
}

// Round 10
// 61.924 us; speedup vs baseline: 3.7736x; 1.0845x over previous
//
#include <hip/hip_runtime.h>
#include <stdint.h>

#define TPB 64
#define RCAP 64
#define BAND 0.05f

// d_ws layout (u32 words)
#define WS_BFR   0     // 1280: B fragments [s 5][lane 64][dw 4] (f16, n=2c+dy trick)
#define WS_W1B   1280  // 18:  w1 sign bits [6 c][3 words] (bit k = ic*25+kr*5+kc)
#define WS_W2PK  1298  // 80:  w2 bits [16 oc][5 kr], bit (5c+k)
#define WS_WF1P  1378  // 3000: wf1 bits [120 o][25 pos], bit oc
#define WS_WF2PK 4380  // 336: wf2 bits [84 o][4 q]   (16B-aligned base)
#define WS_WF3PK 4716  // 30:  wf3 bits [10 o][3 q]   (end 4746)

typedef _Float16 half8 __attribute__((ext_vector_type(8)));
typedef float f32x4 __attribute__((ext_vector_type(4)));
typedef unsigned int u32x4 __attribute__((ext_vector_type(4)));

__device__ __forceinline__ uint32_t pkf16(float a, float b) {
  uint32_t lo = (uint32_t)__builtin_bit_cast(uint16_t, (_Float16)a);
  uint32_t hi = (uint32_t)__builtin_bit_cast(uint16_t, (_Float16)b);
  return lo | (hi << 16);
}

// lane^1 exchange on the VALU pipe (DPP quad_perm [1,0,3,2]) — not the LDS pipe
__device__ __forceinline__ float qpswap(float v) {
  return __builtin_bit_cast(float, __builtin_amdgcn_mov_dpp(
      __builtin_bit_cast(int, v), 0xB1, 0xF, 0xF, true));
}

// exact fp64 window sum from global x; weights as sign bits b0/b1/b2
__device__ __forceinline__ double win_sum(const float* __restrict__ xb,
                                          uint32_t b0, uint32_t b1, uint32_t b2) {
  double s = 0.0;
#pragma unroll
  for (int ic = 0; ic < 3; ++ic)
#pragma unroll
    for (int rr = 0; rr < 5; ++rr) {
      const float* rp = xb + ic * 1024 + rr * 32;
#pragma unroll
      for (int kc = 0; kc < 5; ++kc) {
        const int idx = ic * 25 + rr * 5 + kc;
        const uint32_t bw = (idx < 32) ? b0 : ((idx < 64) ? b1 : b2);
        double xv = (double)rp[kc];
        s += ((bw >> (idx & 31)) & 1u) ? xv : -xv;
      }
    }
  return s;
}

__global__ __launch_bounds__(256) void prep_kernel(
    const float* __restrict__ w1, const float* __restrict__ w2,
    const float* __restrict__ wf1, const float* __restrict__ wf2,
    const float* __restrict__ wf3, uint32_t* __restrict__ wsu)
{
  int id = blockIdx.x * 256 + threadIdx.x;
  if (id < 1280) {
    // B fragment, dy-in-N: n = 2c+dy (n<12). k-octet o = 4s+g4 -> input row
    // r6 = o/3 (0..5), col-pair cp = o%3. k-slot j2 = dw*2+h ->
    // ic = j2&3, pixel = j2>>2, kc = cp*2+pixel; tap kr = r6-dy must be 0..4.
    int s = id >> 8, r = id & 255, ln = r >> 2, dw = r & 3;
    int g4 = ln >> 4, n = ln & 15;
    int o = 4 * s + g4, r6 = o / 3, cp = o % 3;
    int c = n >> 1, dy = n & 1;
    uint32_t w = 0;
    for (int h = 0; h < 2; ++h) {
      int j2 = dw * 2 + h;
      int ic = j2 & 3, pix = j2 >> 2, kc = cp * 2 + pix, kr = r6 - dy;
      uint32_t f = 0;
      if (n < 12 && o < 18 && ic < 3 && kc < 5 && kr >= 0 && kr <= 4)
        f = (w1[(c * 3 + ic) * 25 + kr * 5 + kc] >= 0.f) ? 0x3C00u : 0xBC00u;
      w |= f << (16 * h);
    }
    wsu[WS_BFR + id] = w;
  } else if (id < 1298) {
    int i = id - 1280, c = i / 3, q = i % 3;
    uint32_t w = 0;
    for (int b = 0; b < 32; ++b) {
      int k = q * 32 + b;
      if (k < 75) w |= (uint32_t)(w1[c*75 + k] >= 0.f) << b;
    }
    wsu[WS_W1B + i] = w;
  } else if (id < 1378) {
    int r = id - 1298, oc = r / 5, kr = r % 5;
    uint32_t w = 0;
    for (int c = 0; c < 6; ++c)
      for (int k = 0; k < 5; ++k)
        w |= (uint32_t)(w2[((oc*6 + c)*5 + kr)*5 + k] >= 0.f) << (5*c + k);
    wsu[WS_W2PK + r] = w;
  } else if (id < 4378) {
    int r = id - 1378, o = r / 25, p = r % 25;
    uint32_t w = 0;
    for (int oc = 0; oc < 16; ++oc)
      w |= (uint32_t)(wf1[o*400 + oc*25 + p] >= 0.f) << oc;
    wsu[WS_WF1P + r] = w;
  } else if (id >= 4380 && id < 4716) {
    int r = id - 4380, o = r / 4, q = r % 4;
    uint32_t w = 0;
    for (int b = 0; b < 32; ++b) {
      int n = q*32 + b;
      if (n < 120) w |= (uint32_t)(wf2[o*120 + n] >= 0.f) << b;
    }
    wsu[WS_WF2PK + r] = w;
  } else if (id >= 4716 && id < 4746) {
    int r = id - 4716, o = r / 3, q = r % 3;
    uint32_t w = 0;
    for (int b = 0; b < 32; ++b) {
      int n = q*32 + b;
      if (n < 84) w |= (uint32_t)(wf3[o*84 + n] >= 0.f) << b;
    }
    wsu[WS_WF3PK + r] = w;
  }
}

// One wave = one block = one image. LDS is reserved for conv1 staging only;
// conv2 runs in registers (scalar w2 loads), fc1-3 are LDS-free (ballot words).
__global__ void __launch_bounds__(TPB, 4) lenet_kernel(
    const float* __restrict__ x,
    const float* __restrict__ b1, const float* __restrict__ b2,
    const float* __restrict__ bf1, const float* __restrict__ bf2,
    const float* __restrict__ bf3,
    const uint32_t* __restrict__ wsu,
    float* __restrict__ out)
{
  // Image: [row 32][col 33] pixels of 8B ({f16 c0,c1} {f16 c2,0}); col 32 = zero pad.
  __shared__ __align__(16) uint32_t imgh[2112];   // 8448 B
  __shared__ uint32_t bits1[6][14];               // fully overwritten by conv1
  __shared__ uint32_t border_[6][14];             // fully overwritten by conv1
  __shared__ uint32_t bits2s[25];                 // fully overwritten by conv2
  __shared__ uint32_t rlist[RCAP];
  __shared__ int rcnt;

  const int t = threadIdx.x;                  // lane 0..63
  const int m16 = t & 15;                     // A-row = x position
  const int g4 = t >> 4;                      // k-octet group
  const long long img = blockIdx.x;

  // conv1 B fragments + per-step k-octet offsets (global, L2/L3-resident)
  u32x4 bfr[5];
#pragma unroll
  for (int s = 0; s < 5; ++s)
    bfr[s] = *(const u32x4*)&wsu[WS_BFR + (s << 8) + (t << 2)];
  int koffs[5];
#pragma unroll
  for (int s = 0; s < 5; ++s) {
    const int o = 4 * s + g4;
    koffs[s] = (o < 18) ? (o / 3) * 33 + (o % 3) * 2 : 0;  // o>=18: B=0
  }

  // ---------- load + f16 interleave pack (fully static indexing) ----------
  {
    const int y = t >> 1, xh = t & 1;
    const float* rp = x + img * 3072 + y * 32 + xh * 16;
    const int pixbase = y * 33 + xh * 16;
#pragma unroll
    for (int q = 0; q < 4; ++q) {
      float4 f0 = *(const float4*)(rp +    0 + 4 * q);
      float4 f1 = *(const float4*)(rp + 1024 + 4 * q);
      float4 f2 = *(const float4*)(rp + 2048 + 4 * q);
      uint32_t* d = &imgh[2 * (pixbase + 4 * q)];
      *(uint2*)(d + 0) = make_uint2(pkf16(f0.x, f1.x), pkf16(f2.x, 0.f));
      *(uint2*)(d + 2) = make_uint2(pkf16(f0.y, f1.y), pkf16(f2.y, 0.f));
      *(uint2*)(d + 4) = make_uint2(pkf16(f0.z, f1.z), pkf16(f2.z, 0.f));
      *(uint2*)(d + 6) = make_uint2(pkf16(f0.w, f1.w), pkf16(f2.w, 0.f));
    }
    if (t < 32)  // zero pad col 32 of every row
      *(uint2*)&imgh[2 * (t * 33 + 32)] = make_uint2(0u, 0u);
    if (t == 0) rcnt = 0;
  }
  __syncthreads();

  // ---------- conv1: f16 MFMA dy-in-N; per pyi: 2 interleaved xg chains ----------
  {
    const int n = m16;
    const int c = n >> 1;
    const float bcr = b1[(n < 12) ? c : 0];   // per-lane global (L3)
    for (int pyi = 0; pyi < 14; ++pyi) {
      const int rowpix = (2 * pyi) * 33 + m16;
      f32x4 aX = {0.f, 0.f, 0.f, 0.f}, aY = {0.f, 0.f, 0.f, 0.f};
#pragma unroll
      for (int s = 0; s < 5; ++s) {
        const uint2* pX = (const uint2*)&imgh[2 * (rowpix + koffs[s])];
        const uint2* pY = (const uint2*)&imgh[2 * (rowpix + 12 + koffs[s])];
        uint2 x0 = pX[0], x1 = pX[1];
        uint2 y0 = pY[0], y1 = pY[1];
        u32x4 wa = {x0.x, x0.y, x1.x, x1.y};
        u32x4 wb = {y0.x, y0.y, y1.x, y1.y};
        aX = __builtin_amdgcn_mfma_f32_16x16x32_f16(
               __builtin_bit_cast(half8, wa), __builtin_bit_cast(half8, bfr[s]), aX, 0, 0, 0);
        aY = __builtin_amdgcn_mfma_f32_16x16x32_f16(
               __builtin_bit_cast(half8, wb), __builtin_bit_cast(half8, bfr[s]), aY, 0, 0, 0);
      }
      // x-pair pool in-lane (rows g4*4+q); dy-pair pool via DPP lane^1 (VALU pipe)
      float pX0 = fmaxf(aX[0], aX[1]), pX1 = fmaxf(aX[2], aX[3]);
      float pY0 = fmaxf(aY[0], aY[1]), pY1 = fmaxf(aY[2], aY[3]);
      float qX0 = fmaxf(pX0, qpswap(pX0));
      float qX1 = fmaxf(pX1, qpswap(pX1));
      float qY0 = fmaxf(pY0, qpswap(pY0));
      float qY1 = fmaxf(pY1, qpswap(pY1));
      uint32_t comb = 0;
      {
        float v0 = qX0 + bcr, v1 = qX1 + bcr, v2 = qY0 + bcr, v3 = qY1 + bcr;
        const int p0 = g4 * 2, p1 = g4 * 2 + 1, p2 = 6 + g4 * 2, p3 = 7 + g4 * 2;
        if (fabsf(v0) < BAND) comb |= 1u << (16 + p0); else if (v0 >= 0.f) comb |= 1u << p0;
        if (fabsf(v1) < BAND) comb |= 1u << (16 + p1); else if (v1 >= 0.f) comb |= 1u << p1;
        if (fabsf(v2) < BAND) comb |= 1u << (16 + p2); else if (v2 >= 0.f) comb |= 1u << p2;
        if (fabsf(v3) < BAND) comb |= 1u << (16 + p3); else if (v3 >= 0.f) comb |= 1u << p3;
      }
      comb |= __shfl_xor(comb, 16);
      comb |= __shfl_xor(comb, 32);
      if (g4 == 0 && n < 12 && (n & 1) == 0) {
        bits1[c][pyi]   = comb & 0x3FFFu;
        border_[c][pyi] = comb >> 16;
      }
    }
  }
  __syncthreads();

  // ---------- borderline list build ----------
  for (int id = t; id < 84; id += TPB) {
    uint32_t bw = ((uint32_t*)border_)[id];
    while (bw) {
      int pj = __ffs(bw) - 1;
      bw &= bw - 1;
      int slot = atomicAdd(&rcnt, 1);
      if (slot < RCAP) rlist[slot] = (uint32_t)(id * 16 + pj);
    }
  }
  __syncthreads();

  // ---------- exact fp64 resolve from global (one window per lane; cold) ----------
  {
    const int cnt = min(rcnt, RCAP);
    for (int k = t; k < cnt * 4; k += TPB) {
      const int e = k >> 2, win = k & 3;
      const uint32_t ent = rlist[e];
      const int pj = ent & 15, w = ent >> 4;
      const int pi = w % 14, c = w / 14;
      const int dr = win >> 1, dc = win & 1;
      const float* xb = x + img * 3072 + (2*pi + dr) * 32 + (2*pj + dc);
      double s = win_sum(xb, wsu[WS_W1B + c*3], wsu[WS_W1B + c*3+1], wsu[WS_W1B + c*3+2]);
      double s1 = fmax(s, __shfl_xor(s, 1));
      double sm = fmax(s1, __shfl_xor(s1, 2));
      if (win == 0) {
        if (sm + (double)b1[c] >= 0.0)
          atomicOr(&((uint32_t*)bits1)[w], 1u << pj);
      }
    }
    if (rcnt > RCAP) {  // fallback (never in practice): rescan all masks
      for (int id = t; id < 1176; id += TPB) {
        const int w = id / 14, pj = id % 14;
        if ((((uint32_t*)border_)[w] >> pj) & 1u) {
          const int pi = w % 14, c = w / 14;
          double best = -1e300;
          for (int dr = 0; dr < 2; ++dr)
            for (int dc = 0; dc < 2; ++dc) {
              const float* xb = x + img * 3072 + (2*pi + dr) * 32 + (2*pj + dc);
              double s = win_sum(xb, wsu[WS_W1B + c*3], wsu[WS_W1B + c*3+1], wsu[WS_W1B + c*3+2]);
              best = best > s ? best : s;
            }
          if (best + (double)b1[c] >= 0.0)
            atomicOr(&((uint32_t*)bits1)[w], 1u << pj);
        }
      }
    }
  }
  __syncthreads();

  // ---------- conv2: register ppatch + scalar w2 + bpermute pooling ----------
  {
    const int la  = (t < 50) ? t : 49;      // lanes 50-63 mirror lane 49 (discarded)
    const int i   = la / 5;                 // unpooled row 0..9
    const int pjc = la % 5;                 // pooled col
    const int j0  = 2 * pjc;
    uint32_t ppA[5], ppB[5];
#pragma unroll
    for (int kr = 0; kr < 5; ++kr) {
      uint32_t wa = 0, wb = 0;
#pragma unroll
      for (int c = 0; c < 6; ++c) {
        uint32_t bc = bits1[c][i + kr];     // broadcast-clean b32 reads
        wa |= ((bc >> j0) & 31u) << (5*c);
        wb |= ((bc >> (j0 + 1)) & 31u) << (5*c);
      }
      ppA[kr] = wa; ppB[kr] = wb;
    }
    const int partner = (i & 1) ? (la - 5) : (la + 5);
    uint32_t myword = 0;
#pragma unroll 4
    for (int oc = 0; oc < 16; ++oc) {
      int dA = 0, dB = 0;
#pragma unroll
      for (int kr = 0; kr < 5; ++kr) {
        const uint32_t wv = wsu[WS_W2PK + oc*5 + kr];   // uniform -> s_load
        dA += __popc(ppA[kr] ^ wv);
        dB += __popc(ppB[kr] ^ wv);
      }
      int dm = min(dA, dB);
      int dp = __shfl(dm, partner);
      int dmin = min(dm, dp);
      float v = (float)(150 - 2*dmin) + b2[oc];          // uniform bias -> s_load
      myword |= (v >= 0.f ? 1u : 0u) << oc;
    }
    if (t < 50 && (i & 1) == 0) bits2s[(i >> 1) * 5 + pjc] = myword;
  }
  __syncthreads();

  // ---------- fc1: bits2 broadcast to regs, wf1 rows from global, ballot out ----------
  uint32_t f1w0, f1w1, f1w2, f1w3;
  {
    uint32_t p2[25];
#pragma unroll
    for (int p = 0; p < 25; ++p) p2[p] = bits2s[p];
    const uint32_t* wrA = wsu + WS_WF1P + t * 25;
    int d1 = 0;
#pragma unroll
    for (int p = 0; p < 25; ++p) d1 += __popc(p2[p] ^ wrA[p]);
    float v1 = (float)(400 - 2*d1) + bf1[t];
    const bool act2 = (t < 56);
    const int o2 = 64 + t;
    int d2 = 0;
    const uint32_t* wrB = wsu + WS_WF1P + o2 * 25;
    if (act2) {
#pragma unroll
      for (int p = 0; p < 25; ++p) d2 += __popc(p2[p] ^ wrB[p]);
    }
    float v2 = act2 ? ((float)(400 - 2*d2) + bf1[o2]) : -1.f;
    unsigned long long mA = __ballot(v1 >= 0.f);
    unsigned long long mB = __ballot(act2 && (v2 >= 0.f));
    f1w0 = (uint32_t)mA; f1w1 = (uint32_t)(mA >> 32);
    f1w2 = (uint32_t)mB; f1w3 = (uint32_t)(mB >> 32);
  }

  // ---------- fc2: wave-uniform activations, per-lane wf2 rows, ballot out ----------
  uint32_t f2w0, f2w1, f2w2;
  {
    const uint32_t* wr = wsu + WS_WF2PK + t * 4;
    int d3 = __popc(f1w0 ^ wr[0]) + __popc(f1w1 ^ wr[1]) +
             __popc(f1w2 ^ wr[2]) + __popc(f1w3 ^ wr[3]);
    float v3 = (float)(120 - 2*d3) + bf2[t];            // t<84 always
    const bool act4 = (t < 20);
    const int o4 = 64 + t;
    const uint32_t* wr2 = wsu + WS_WF2PK + o4 * 4;
    int d4 = 0;
    if (act4)
      d4 = __popc(f1w0 ^ wr2[0]) + __popc(f1w1 ^ wr2[1]) +
           __popc(f1w2 ^ wr2[2]) + __popc(f1w3 ^ wr2[3]);
    float v4 = act4 ? ((float)(120 - 2*d4) + bf2[o4]) : -1.f;
    unsigned long long mC = __ballot(v3 >= 0.f);
    unsigned long long mD = __ballot(act4 && (v4 >= 0.f));
    f2w0 = (uint32_t)mC; f2w1 = (uint32_t)(mC >> 32); f2w2 = (uint32_t)mD;
  }

  // ---------- fc3 ----------
  if (t < 10) {
    int d = __popc(f2w0 ^ wsu[WS_WF3PK + t*3 + 0]) +
            __popc(f2w1 ^ wsu[WS_WF3PK + t*3 + 1]) +
            __popc(f2w2 ^ wsu[WS_WF3PK + t*3 + 2]);
    out[img*10 + t] = (float)(84 - 2*d) + bf3[t];
  }
}

extern "C" void kernel_launch(void* const* d_in, const int* in_sizes, int n_in,
                              void* d_out, int out_size, void* d_ws, size_t ws_size,
                              hipStream_t stream)
{
  const float* x   = (const float*)d_in[0];
  const float* w1  = (const float*)d_in[1];
  const float* b1  = (const float*)d_in[2];
  const float* w2  = (const float*)d_in[3];
  const float* b2  = (const float*)d_in[4];
  const float* wf1 = (const float*)d_in[5];
  const float* bf1 = (const float*)d_in[6];
  const float* wf2 = (const float*)d_in[7];
  const float* bf2 = (const float*)d_in[8];
  const float* wf3 = (const float*)d_in[9];
  const float* bf3 = (const float*)d_in[10];
  uint32_t* wsu = (uint32_t*)d_ws;

  const int imgs = in_sizes[0] / 3072;
  hipLaunchKernelGGL(prep_kernel, dim3(19), dim3(256), 0, stream,
                     w1, w2, wf1, wf2, wf3, wsu);
  hipLaunchKernelGGL(lenet_kernel, dim3(imgs), dim3(TPB), 0, stream,
                     x, b1, b2, bf1, bf2, bf3, wsu, (float*)d_out);
}